// Round 1
// baseline (947.683 us; speedup 1.0000x reference)
//
#include <hip/hip_runtime.h>
#include <hip/hip_bf16.h>

typedef __hip_bfloat16 bf16;
typedef __hip_bfloat162 bf16x2;

__device__ __forceinline__ float toF(float v) { return v; }
__device__ __forceinline__ float toF(bf16 v) { return __bfloat162float(v); }
__device__ __forceinline__ void storeOut(float* p, float v) { *p = v; }
__device__ __forceinline__ void storeOut(bf16* p, float v) { *p = __float2bfloat16(v); }

// ---------------- GEMM: C[M,N] = A[M,K] @ B[K,N] (+bias) ----------------
// 64x64 tile, 256 threads, 4x4 microtile, fp32 accumulate.
template<typename TA, typename TC, bool BIAS>
__global__ __launch_bounds__(256) void gemm64(const TA* __restrict__ A,
                                              const float* __restrict__ Bm,
                                              const float* __restrict__ bias,
                                              TC* __restrict__ Cm,
                                              int M, int N, int K)
{
  __shared__ float As[16][68];
  __shared__ float Bs[16][68];
  const int bm = blockIdx.y * 64;
  const int bn = blockIdx.x * 64;
  const int tid = threadIdx.x;
  const int tx = tid & 15, ty = tid >> 4;
  float acc[4][4] = {};
  for (int k0 = 0; k0 < K; k0 += 16) {
#pragma unroll
    for (int e = 0; e < 4; ++e) {
      int idx = tid + e * 256;           // 1024 = 64 rows x 16 k
      int m = idx >> 4, kk = idx & 15;
      As[kk][m] = toF(A[(size_t)(bm + m) * K + k0 + kk]);
    }
#pragma unroll
    for (int e = 0; e < 4; ++e) {
      int idx = tid + e * 256;           // 1024 = 16 k x 64 cols
      int kk = idx >> 6, n = idx & 63;
      Bs[kk][n] = Bm[(size_t)(k0 + kk) * N + bn + n];
    }
    __syncthreads();
#pragma unroll
    for (int kk = 0; kk < 16; ++kk) {
      float4 a4 = *(const float4*)&As[kk][ty * 4];
      float4 b4 = *(const float4*)&Bs[kk][tx * 4];
      float a[4] = {a4.x, a4.y, a4.z, a4.w};
      float b[4] = {b4.x, b4.y, b4.z, b4.w};
#pragma unroll
      for (int i = 0; i < 4; ++i)
#pragma unroll
        for (int j = 0; j < 4; ++j) acc[i][j] += a[i] * b[j];
    }
    __syncthreads();
  }
#pragma unroll
  for (int i = 0; i < 4; ++i) {
    int m = bm + ty * 4 + i;
#pragma unroll
    for (int j = 0; j < 4; ++j) {
      int n = bn + tx * 4 + j;
      float v = acc[i][j];
      if (BIAS) v += bias[n];
      storeOut(&Cm[(size_t)m * N + n], v);
    }
  }
}

// ---------------- Pooling: mean + max over k x k blocks ----------------
// one block (128 threads = channels) per output position (s,b,y,x)
__global__ __launch_bounds__(128) void pool_kernel(const bf16* __restrict__ temp,
                                                   bf16* __restrict__ outp,
                                                   int oh, int ow, int k, int i_scale)
{
  int blk = blockIdx.x;
  int c = threadIdx.x;
  int x = blk % ow; int t = blk / ow;
  int y = t % oh;  t /= oh;
  int b = t % 16;  int s = t / 16;
  float sum = 0.f, mx = -3.4e38f;
  float inv = 1.0f / (float)(k * k);
  for (int dy = 0; dy < k; ++dy)
    for (int dx = 0; dx < k; ++dx) {
      int h = y * k + dy, w = x * k + dx;
      float v = __bfloat162float(temp[((size_t)b * 3136 + h * 56 + w) * 1152 + s * 384 + i_scale * 128 + c]);
      sum += v; mx = fmaxf(mx, v);
    }
  outp[((size_t)(s * 16 + b) * oh * ow + y * ow + x) * 128 + c] = __float2bfloat16(sum * inv + mx);
}

// ---------------- Window attention (4 heads, P=49, hd=32) ----------------
// Matches the reference's scrambled grouping:
//   bias head = r % 4 (for all 4 data heads in window r)
//   output: channel (r&3)*32+d, spatial m = (l*(R/4)+(r>>2))*49+p (raster)
__global__ __launch_bounds__(256) void attn_kernel(
    const bf16* __restrict__ qb, const bf16* __restrict__ kb, const bf16* __restrict__ vb,
    const float* __restrict__ btable, bf16* __restrict__ out,
    int R, int Rw, int ow, int npos,
    long long bstride, int rstride, int out_cstride, int out_coffset)
{
  __shared__ float ks[49][132];
  __shared__ float vs[49][132];
  __shared__ float bs[49][53];
  const int blk = blockIdx.x;
  const int b = blk / R, r = blk % R;
  const int rh = r / Rw, rw = r % Rw;
  const int tid = threadIdx.x;
  const int hb = r & 3;

  // stage K,V (49 positions x 128 ch, as 64 bf16x2 pairs per row)
  for (int idx = tid; idx < 49 * 64; idx += 256) {
    int row = idx >> 6, cp = idx & 63;
    int n = (rh * 7 + row / 7) * ow + (rw * 7 + row % 7);
    size_t base = (size_t)b * bstride + (size_t)n * rstride + cp * 2;
    bf16x2 k2 = *(const bf16x2*)(kb + base);
    bf16x2 v2 = *(const bf16x2*)(vb + base);
    *(float2*)&ks[row][cp * 2] = make_float2(__bfloat162float(k2.x), __bfloat162float(k2.y));
    *(float2*)&vs[row][cp * 2] = make_float2(__bfloat162float(v2.x), __bfloat162float(v2.y));
  }
  // stage bias slice for head hb
  for (int idx = tid; idx < 49 * 49; idx += 256) {
    int p = idx / 49, pp = idx % 49;
    int rid = (p / 7 - pp / 7 + 6) * 13 + (p % 7 - pp % 7 + 6);
    bs[p][pp] = btable[rid * 4 + hb];
  }
  __syncthreads();

  if (tid < 196) {
    const int l = tid / 49, p = tid % 49;
    const int n = (rh * 7 + p / 7) * ow + (rw * 7 + p % 7);
    const float scale = 0.17677669529663687f;  // 32^-0.5
    float qreg[32];
    const bf16* qp = qb + (size_t)b * bstride + (size_t)n * rstride + l * 32;
#pragma unroll
    for (int d2 = 0; d2 < 16; ++d2) {
      bf16x2 q2 = *(const bf16x2*)(qp + d2 * 2);
      qreg[d2 * 2 + 0] = __bfloat162float(q2.x) * scale;
      qreg[d2 * 2 + 1] = __bfloat162float(q2.y) * scale;
    }
    float rowv[49];
#pragma unroll
    for (int pp = 0; pp < 49; ++pp) {
      const float* kr = &ks[pp][l * 32];
      float dot = 0.f;
#pragma unroll
      for (int c4 = 0; c4 < 8; ++c4) {
        float4 k4 = *(const float4*)(kr + c4 * 4);
        dot += qreg[c4 * 4 + 0] * k4.x + qreg[c4 * 4 + 1] * k4.y +
               qreg[c4 * 4 + 2] * k4.z + qreg[c4 * 4 + 3] * k4.w;
      }
      rowv[pp] = dot + bs[p][pp];
    }
    float mx = rowv[0];
#pragma unroll
    for (int pp = 1; pp < 49; ++pp) mx = fmaxf(mx, rowv[pp]);
    float sum = 0.f;
#pragma unroll
    for (int pp = 0; pp < 49; ++pp) { rowv[pp] = __expf(rowv[pp] - mx); sum += rowv[pp]; }
    float inv = 1.0f / sum;
    float acc[32] = {};
#pragma unroll
    for (int pp = 0; pp < 49; ++pp) {
      float w = rowv[pp];
      const float* vr = &vs[pp][l * 32];
#pragma unroll
      for (int c4 = 0; c4 < 8; ++c4) {
        float4 v4 = *(const float4*)(vr + c4 * 4);
        acc[c4 * 4 + 0] += w * v4.x; acc[c4 * 4 + 1] += w * v4.y;
        acc[c4 * 4 + 2] += w * v4.z; acc[c4 * 4 + 3] += w * v4.w;
      }
    }
    const int m_out = (l * (R >> 2) + (r >> 2)) * 49 + p;
    const int c0 = (r & 3) * 32;
    bf16* op = out + ((size_t)b * npos + m_out) * out_cstride + out_coffset + c0;
#pragma unroll
    for (int d2 = 0; d2 < 16; ++d2) {
      bf16x2 o2;
      o2.x = __float2bfloat16(acc[d2 * 2 + 0] * inv);
      o2.y = __float2bfloat16(acc[d2 * 2 + 1] * inv);
      *(bf16x2*)(op + d2 * 2) = o2;
    }
  }
}

// ---------------- Bilinear upsample (jax half-pixel, clamped) ----------------
__global__ __launch_bounds__(128) void upsample_kernel(const bf16* __restrict__ ybuf,
                                                       bf16* __restrict__ fused,
                                                       int oh, int ow, int coffset)
{
  int blk = blockIdx.x;           // b*3136 + n
  int c = threadIdx.x;            // 0..127
  int n = blk % 3136, b = blk / 3136;
  int h = n / 56, w = n % 56;
  float ry = (float)oh / 56.f, rx = (float)ow / 56.f;
  float uy = (h + 0.5f) * ry - 0.5f;
  float ux = (w + 0.5f) * rx - 0.5f;
  float fy0 = floorf(uy), fx0 = floorf(ux);
  int y0 = (int)fy0, x0 = (int)fx0;
  float fy = uy - fy0, fx = ux - fx0;
  int y0c = max(y0, 0), y1c = min(y0 + 1, oh - 1);
  int x0c = max(x0, 0), x1c = min(x0 + 1, ow - 1);
  const bf16* base = ybuf + (size_t)b * oh * ow * 128;
  float v00 = __bfloat162float(base[((size_t)y0c * ow + x0c) * 128 + c]);
  float v01 = __bfloat162float(base[((size_t)y0c * ow + x1c) * 128 + c]);
  float v10 = __bfloat162float(base[((size_t)y1c * ow + x0c) * 128 + c]);
  float v11 = __bfloat162float(base[((size_t)y1c * ow + x1c) * 128 + c]);
  float v = (1.f - fy) * ((1.f - fx) * v00 + fx * v01) + fy * ((1.f - fx) * v10 + fx * v11);
  fused[((size_t)b * 3136 + n) * 384 + coffset + c] = __float2bfloat16(v);
}

extern "C" void kernel_launch(void* const* d_in, const int* in_sizes, int n_in,
                              void* d_out, int out_size, void* d_ws, size_t ws_size,
                              hipStream_t stream)
{
  const float* x      = (const float*)d_in[0];
  const float* w_qkv  = (const float*)d_in[1];
  const float* w_proj = (const float*)d_in[2];
  const float* b_proj = (const float*)d_in[3];
  const float* btable = (const float*)d_in[4];
  // d_in[5], d_in[6] = H, W (fixed 56)

  bf16* temp  = (bf16*)d_ws;                          // 50176 x 1152
  bf16* pool1 = temp  + (size_t)50176 * 1152;         // 3 x 16 x 784 x 128
  bf16* pool2 = pool1 + (size_t)3 * 16 * 784 * 128;   // 3 x 16 x 196 x 128
  bf16* fused = pool2 + (size_t)3 * 16 * 196 * 128;   // 50176 x 384
  bf16* ybuf1 = fused + (size_t)50176 * 384;          // 16 x 784 x 128
  bf16* ybuf2 = ybuf1 + (size_t)16 * 784 * 128;       // 16 x 196 x 128

  // 1) QKV projection: temp = x @ w_qkv  (bf16 out)
  gemm64<float, bf16, false><<<dim3(18, 784), 256, 0, stream>>>(
      x, w_qkv, nullptr, temp, 50176, 1152, 384);

  // 2) pooling for scales 1,2 (mean + max)
  pool_kernel<<<3 * 16 * 28 * 28, 128, 0, stream>>>(temp, pool1, 28, 28, 2, 1);
  pool_kernel<<<3 * 16 * 14 * 14, 128, 0, stream>>>(temp, pool2, 14, 14, 4, 2);

  // 3) window attention per scale
  attn_kernel<<<16 * 64, 256, 0, stream>>>(
      temp, temp + 384, temp + 768, btable, fused,
      64, 8, 56, 3136, (long long)3136 * 1152, 1152, 384, 0);
  attn_kernel<<<16 * 16, 256, 0, stream>>>(
      pool1, pool1 + (size_t)16 * 784 * 128, pool1 + (size_t)2 * 16 * 784 * 128,
      btable, ybuf1, 16, 4, 28, 784, (long long)784 * 128, 128, 128, 0);
  attn_kernel<<<16 * 4, 256, 0, stream>>>(
      pool2, pool2 + (size_t)16 * 196 * 128, pool2 + (size_t)2 * 16 * 196 * 128,
      btable, ybuf2, 4, 2, 14, 196, (long long)196 * 128, 128, 128, 0);

  // 4) bilinear upsample scales 1,2 into fused channels [128,256) and [256,384)
  upsample_kernel<<<16 * 3136, 128, 0, stream>>>(ybuf1, fused, 28, 28, 128);
  upsample_kernel<<<16 * 3136, 128, 0, stream>>>(ybuf2, fused, 14, 14, 256);

  // 5) output projection: out = fused @ w_proj + b_proj (fp32 out)
  gemm64<bf16, float, true><<<dim3(6, 784), 256, 0, stream>>>(
      fused, w_proj, b_proj, (float*)d_out, 50176, 384, 384);
}

// Round 2
// 324.935 us; speedup vs baseline: 2.9165x; 2.9165x over previous
//
#include <hip/hip_runtime.h>
#include <hip/hip_bf16.h>

typedef __hip_bfloat16 bf16;
typedef __hip_bfloat162 bf16x2;
typedef __attribute__((ext_vector_type(8))) short short8;
typedef __attribute__((ext_vector_type(4))) float f32x4;

__device__ __forceinline__ void storeOut(float* p, float v) { *p = v; }
__device__ __forceinline__ void storeOut(bf16* p, float v) { *p = __float2bfloat16(v); }

#define GLOAD_LDS16(g, l)                                              \
  __builtin_amdgcn_global_load_lds(                                    \
      (const __attribute__((address_space(1))) void*)(g),              \
      (__attribute__((address_space(3))) void*)(l), 16, 0, 0)

// ---------------- fp32 -> bf16 bulk convert (8 elems/thread) ----------------
__global__ __launch_bounds__(256) void cvt_f32_bf16_kernel(const float* __restrict__ in,
                                                           bf16* __restrict__ out, int n8)
{
  int i = blockIdx.x * 256 + threadIdx.x;
  if (i >= n8) return;
  const float4* p = (const float4*)in + (size_t)i * 2;
  float4 a = p[0], b = p[1];
  union { short8 v; bf16 h[8]; } u;
  u.h[0] = __float2bfloat16(a.x); u.h[1] = __float2bfloat16(a.y);
  u.h[2] = __float2bfloat16(a.z); u.h[3] = __float2bfloat16(a.w);
  u.h[4] = __float2bfloat16(b.x); u.h[5] = __float2bfloat16(b.y);
  u.h[6] = __float2bfloat16(b.z); u.h[7] = __float2bfloat16(b.w);
  *((short8*)out + i) = u.v;
}

// ---------------- weight transpose fp32[K][N] -> bf16[N][K] ----------------
__global__ __launch_bounds__(256) void transpose_f2b_kernel(const float* __restrict__ in,
                                                            bf16* __restrict__ out, int K, int N)
{
  int idx = blockIdx.x * 256 + threadIdx.x;
  if (idx >= K * N) return;
  int n = idx / K, k = idx - n * K;
  out[idx] = __float2bfloat16(in[(size_t)k * N + n]);
}

// ---------------- MFMA GEMM: C[M,N] = A[M,K] @ Bt[N,K]^T (+bias) ----------------
// 128x128 tile, BK=32, 4 waves each computing 64x64 via 4x4 16x16x32 bf16 MFMA.
// m97 structure: global_load_lds(16B) staging, 2 barriers per K-step.
template<typename TC, bool BIAS>
__global__ __launch_bounds__(256) void gemm_mfma(const bf16* __restrict__ A,
                                                 const bf16* __restrict__ Bt,
                                                 const float* __restrict__ bias,
                                                 TC* __restrict__ C,
                                                 int M, int N, int K)
{
  __shared__ __align__(16) bf16 As[128 * 32];
  __shared__ __align__(16) bf16 Bs[128 * 32];
  const int tid = threadIdx.x;
  const int wave = tid >> 6, lane = tid & 63;
  const int bm = blockIdx.y * 128, bn = blockIdx.x * 128;
  const int wr = wave >> 1, wc = wave & 1;

  f32x4 acc[4][4] = {};

  // staging: flat byte e*4096 + tid*16 -> row = flat/64, kbyte = flat%64
  const int f0 = tid * 16;
  const int r0 = f0 >> 6, kb0 = f0 & 63;
  const int f1 = 4096 + tid * 16;
  const int r1 = f1 >> 6, kb1 = f1 & 63;
  const bf16* a0 = A + (size_t)(bm + r0) * K + (kb0 >> 1);
  const bf16* a1 = A + (size_t)(bm + r1) * K + (kb1 >> 1);
  const bf16* b0 = Bt + (size_t)(bn + r0) * K + (kb0 >> 1);
  const bf16* b1 = Bt + (size_t)(bn + r1) * K + (kb1 >> 1);
  char* AsW = (char*)As + wave * 1024;   // wave-uniform LDS dest
  char* BsW = (char*)Bs + wave * 1024;

  const int lr = lane & 15, lk = lane >> 4;
  const bf16* ArP = As + (size_t)(wr * 64 + lr) * 32 + lk * 8;
  const bf16* BrP = Bs + (size_t)(wc * 64 + lr) * 32 + lk * 8;

  for (int k0 = 0; k0 < K; k0 += 32) {
    GLOAD_LDS16(a0 + k0, AsW);
    GLOAD_LDS16(a1 + k0, AsW + 4096);
    GLOAD_LDS16(b0 + k0, BsW);
    GLOAD_LDS16(b1 + k0, BsW + 4096);
    __syncthreads();
    short8 af[4], bfr[4];
#pragma unroll
    for (int i = 0; i < 4; ++i) af[i]  = *(const short8*)(ArP + i * 512);
#pragma unroll
    for (int j = 0; j < 4; ++j) bfr[j] = *(const short8*)(BrP + j * 512);
#pragma unroll
    for (int i = 0; i < 4; ++i)
#pragma unroll
      for (int j = 0; j < 4; ++j)
        acc[i][j] = __builtin_amdgcn_mfma_f32_16x16x32_bf16(af[i], bfr[j], acc[i][j], 0, 0, 0);
    __syncthreads();
  }

  // epilogue: C/D layout col=lane&15, row=(lane>>4)*4+t
  const int crow = bm + wr * 64 + lk * 4;
  const int ccol = bn + wc * 64 + lr;
#pragma unroll
  for (int j = 0; j < 4; ++j) {
    int col = ccol + j * 16;
    float bv = BIAS ? bias[col] : 0.f;
#pragma unroll
    for (int i = 0; i < 4; ++i)
#pragma unroll
      for (int t = 0; t < 4; ++t) {
        int row = crow + i * 16 + t;
        storeOut(&C[(size_t)row * N + col], acc[i][j][t] + bv);
      }
  }
}

// ---------------- Pooling: mean + max over k x k blocks ----------------
__global__ __launch_bounds__(128) void pool_kernel(const bf16* __restrict__ temp,
                                                   bf16* __restrict__ outp,
                                                   int oh, int ow, int k, int i_scale)
{
  int blk = blockIdx.x;
  int c = threadIdx.x;
  int x = blk % ow; int t = blk / ow;
  int y = t % oh;  t /= oh;
  int b = t % 16;  int s = t / 16;
  float sum = 0.f, mx = -3.4e38f;
  float inv = 1.0f / (float)(k * k);
  for (int dy = 0; dy < k; ++dy)
    for (int dx = 0; dx < k; ++dx) {
      int h = y * k + dy, w = x * k + dx;
      float v = __bfloat162float(temp[((size_t)b * 3136 + h * 56 + w) * 1152 + s * 384 + i_scale * 128 + c]);
      sum += v; mx = fmaxf(mx, v);
    }
  outp[((size_t)(s * 16 + b) * oh * ow + y * ow + x) * 128 + c] = __float2bfloat16(sum * inv + mx);
}

// ---------------- Window attention (4 heads, P=49, hd=32) ----------------
__global__ __launch_bounds__(256) void attn_kernel(
    const bf16* __restrict__ qb, const bf16* __restrict__ kb, const bf16* __restrict__ vb,
    const float* __restrict__ btable, bf16* __restrict__ out,
    int R, int Rw, int ow, int npos,
    long long bstride, int rstride, int out_cstride, int out_coffset)
{
  __shared__ float ks[49][132];
  __shared__ float vs[49][132];
  __shared__ float bs[49][53];
  const int blk = blockIdx.x;
  const int b = blk / R, r = blk % R;
  const int rh = r / Rw, rw = r % Rw;
  const int tid = threadIdx.x;
  const int hb = r & 3;

  for (int idx = tid; idx < 49 * 64; idx += 256) {
    int row = idx >> 6, cp = idx & 63;
    int n = (rh * 7 + row / 7) * ow + (rw * 7 + row % 7);
    size_t base = (size_t)b * bstride + (size_t)n * rstride + cp * 2;
    bf16x2 k2 = *(const bf16x2*)(kb + base);
    bf16x2 v2 = *(const bf16x2*)(vb + base);
    *(float2*)&ks[row][cp * 2] = make_float2(__bfloat162float(k2.x), __bfloat162float(k2.y));
    *(float2*)&vs[row][cp * 2] = make_float2(__bfloat162float(v2.x), __bfloat162float(v2.y));
  }
  for (int idx = tid; idx < 49 * 49; idx += 256) {
    int p = idx / 49, pp = idx % 49;
    int rid = (p / 7 - pp / 7 + 6) * 13 + (p % 7 - pp % 7 + 6);
    bs[p][pp] = btable[rid * 4 + hb];
  }
  __syncthreads();

  if (tid < 196) {
    const int l = tid / 49, p = tid % 49;
    const int n = (rh * 7 + p / 7) * ow + (rw * 7 + p % 7);
    const float scale = 0.17677669529663687f;
    float qreg[32];
    const bf16* qp = qb + (size_t)b * bstride + (size_t)n * rstride + l * 32;
#pragma unroll
    for (int d2 = 0; d2 < 16; ++d2) {
      bf16x2 q2 = *(const bf16x2*)(qp + d2 * 2);
      qreg[d2 * 2 + 0] = __bfloat162float(q2.x) * scale;
      qreg[d2 * 2 + 1] = __bfloat162float(q2.y) * scale;
    }
    float rowv[49];
#pragma unroll
    for (int pp = 0; pp < 49; ++pp) {
      const float* kr = &ks[pp][l * 32];
      float dot = 0.f;
#pragma unroll
      for (int c4 = 0; c4 < 8; ++c4) {
        float4 k4 = *(const float4*)(kr + c4 * 4);
        dot += qreg[c4 * 4 + 0] * k4.x + qreg[c4 * 4 + 1] * k4.y +
               qreg[c4 * 4 + 2] * k4.z + qreg[c4 * 4 + 3] * k4.w;
      }
      rowv[pp] = dot + bs[p][pp];
    }
    float mx = rowv[0];
#pragma unroll
    for (int pp = 1; pp < 49; ++pp) mx = fmaxf(mx, rowv[pp]);
    float sum = 0.f;
#pragma unroll
    for (int pp = 0; pp < 49; ++pp) { rowv[pp] = __expf(rowv[pp] - mx); sum += rowv[pp]; }
    float inv = 1.0f / sum;
    float acc[32] = {};
#pragma unroll
    for (int pp = 0; pp < 49; ++pp) {
      float w = rowv[pp];
      const float* vr = &vs[pp][l * 32];
#pragma unroll
      for (int c4 = 0; c4 < 8; ++c4) {
        float4 v4 = *(const float4*)(vr + c4 * 4);
        acc[c4 * 4 + 0] += w * v4.x; acc[c4 * 4 + 1] += w * v4.y;
        acc[c4 * 4 + 2] += w * v4.z; acc[c4 * 4 + 3] += w * v4.w;
      }
    }
    const int m_out = (l * (R >> 2) + (r >> 2)) * 49 + p;
    const int c0 = (r & 3) * 32;
    bf16* op = out + ((size_t)b * npos + m_out) * out_cstride + out_coffset + c0;
#pragma unroll
    for (int d2 = 0; d2 < 16; ++d2) {
      bf16x2 o2;
      o2.x = __float2bfloat16(acc[d2 * 2 + 0] * inv);
      o2.y = __float2bfloat16(acc[d2 * 2 + 1] * inv);
      *(bf16x2*)(op + d2 * 2) = o2;
    }
  }
}

// ---------------- Bilinear upsample (jax half-pixel, clamped) ----------------
__global__ __launch_bounds__(128) void upsample_kernel(const bf16* __restrict__ ybuf,
                                                       bf16* __restrict__ fused,
                                                       int oh, int ow, int coffset)
{
  int blk = blockIdx.x;
  int c = threadIdx.x;
  int n = blk % 3136, b = blk / 3136;
  int h = n / 56, w = n % 56;
  float ry = (float)oh / 56.f, rx = (float)ow / 56.f;
  float uy = (h + 0.5f) * ry - 0.5f;
  float ux = (w + 0.5f) * rx - 0.5f;
  float fy0 = floorf(uy), fx0 = floorf(ux);
  int y0 = (int)fy0, x0 = (int)fx0;
  float fy = uy - fy0, fx = ux - fx0;
  int y0c = max(y0, 0), y1c = min(y0 + 1, oh - 1);
  int x0c = max(x0, 0), x1c = min(x0 + 1, ow - 1);
  const bf16* base = ybuf + (size_t)b * oh * ow * 128;
  float v00 = __bfloat162float(base[((size_t)y0c * ow + x0c) * 128 + c]);
  float v01 = __bfloat162float(base[((size_t)y0c * ow + x1c) * 128 + c]);
  float v10 = __bfloat162float(base[((size_t)y1c * ow + x0c) * 128 + c]);
  float v11 = __bfloat162float(base[((size_t)y1c * ow + x1c) * 128 + c]);
  float v = (1.f - fy) * ((1.f - fx) * v00 + fx * v01) + fy * ((1.f - fx) * v10 + fx * v11);
  fused[((size_t)b * 3136 + n) * 384 + coffset + c] = __float2bfloat16(v);
}

extern "C" void kernel_launch(void* const* d_in, const int* in_sizes, int n_in,
                              void* d_out, int out_size, void* d_ws, size_t ws_size,
                              hipStream_t stream)
{
  const float* x      = (const float*)d_in[0];
  const float* w_qkv  = (const float*)d_in[1];
  const float* w_proj = (const float*)d_in[2];
  const float* b_proj = (const float*)d_in[3];
  const float* btable = (const float*)d_in[4];

  bf16* temp  = (bf16*)d_ws;                          // 50176 x 1152
  bf16* pool1 = temp  + (size_t)50176 * 1152;         // 3 x 16 x 784 x 128
  bf16* pool2 = pool1 + (size_t)3 * 16 * 784 * 128;   // 3 x 16 x 196 x 128
  bf16* fused = pool2 + (size_t)3 * 16 * 196 * 128;   // 50176 x 384 (also xb)
  bf16* ybuf1 = fused + (size_t)50176 * 384;          // 16 x 784 x 128
  bf16* ybuf2 = ybuf1 + (size_t)16 * 784 * 128;       // 16 x 196 x 128
  bf16* wqkvT = ybuf2 + (size_t)16 * 196 * 128;       // 1152 x 384
  bf16* wprojT= wqkvT + (size_t)1152 * 384;           // 384 x 384
  bf16* xb    = fused;   // x in bf16, dead before attention writes fused

  // 0) dtype prep
  cvt_f32_bf16_kernel<<<(50176 * 384 / 8 + 255) / 256, 256, 0, stream>>>(x, xb, 50176 * 384 / 8);
  transpose_f2b_kernel<<<(1152 * 384 + 255) / 256, 256, 0, stream>>>(w_qkv, wqkvT, 384, 1152);
  transpose_f2b_kernel<<<(384 * 384 + 255) / 256, 256, 0, stream>>>(w_proj, wprojT, 384, 384);

  // 1) QKV projection: temp = xb @ wqkvT^T
  gemm_mfma<bf16, false><<<dim3(9, 392), 256, 0, stream>>>(
      xb, wqkvT, nullptr, temp, 50176, 1152, 384);

  // 2) pooling for scales 1,2 (mean + max)
  pool_kernel<<<3 * 16 * 28 * 28, 128, 0, stream>>>(temp, pool1, 28, 28, 2, 1);
  pool_kernel<<<3 * 16 * 14 * 14, 128, 0, stream>>>(temp, pool2, 14, 14, 4, 2);

  // 3) window attention per scale
  attn_kernel<<<16 * 64, 256, 0, stream>>>(
      temp, temp + 384, temp + 768, btable, fused,
      64, 8, 56, 3136, (long long)3136 * 1152, 1152, 384, 0);
  attn_kernel<<<16 * 16, 256, 0, stream>>>(
      pool1, pool1 + (size_t)16 * 784 * 128, pool1 + (size_t)2 * 16 * 784 * 128,
      btable, ybuf1, 16, 4, 28, 784, (long long)784 * 128, 128, 128, 0);
  attn_kernel<<<16 * 4, 256, 0, stream>>>(
      pool2, pool2 + (size_t)16 * 196 * 128, pool2 + (size_t)2 * 16 * 196 * 128,
      btable, ybuf2, 4, 2, 14, 196, (long long)196 * 128, 128, 128, 0);

  // 4) bilinear upsample into fused channels [128,256) and [256,384)
  upsample_kernel<<<16 * 3136, 128, 0, stream>>>(ybuf1, fused, 28, 28, 128);
  upsample_kernel<<<16 * 3136, 128, 0, stream>>>(ybuf2, fused, 14, 14, 256);

  // 5) output projection: out = fused @ wprojT^T + b_proj (fp32 out)
  gemm_mfma<float, true><<<dim3(3, 392), 256, 0, stream>>>(
      fused, wprojT, b_proj, (float*)d_out, 50176, 384, 384);
}

// Round 3
// 306.785 us; speedup vs baseline: 3.0891x; 1.0592x over previous
//
#include <hip/hip_runtime.h>
#include <hip/hip_bf16.h>

typedef __hip_bfloat16 bf16;
typedef __hip_bfloat162 bf16x2;
typedef __attribute__((ext_vector_type(8))) short short8;
typedef __attribute__((ext_vector_type(4))) float f32x4;

__device__ __forceinline__ void storeOut(float* p, float v) { *p = v; }
__device__ __forceinline__ void storeOut(bf16* p, float v) { *p = __float2bfloat16(v); }

#define GLOAD_LDS16(g, l)                                              \
  __builtin_amdgcn_global_load_lds(                                    \
      (const __attribute__((address_space(1))) void*)(g),              \
      (__attribute__((address_space(3))) void*)(l), 16, 0, 0)

// ---------------- fp32 -> bf16 bulk convert (8 elems/thread) ----------------
__global__ __launch_bounds__(256) void cvt_f32_bf16_kernel(const float* __restrict__ in,
                                                           bf16* __restrict__ out, int n8)
{
  int i = blockIdx.x * 256 + threadIdx.x;
  if (i >= n8) return;
  const float4* p = (const float4*)in + (size_t)i * 2;
  float4 a = p[0], b = p[1];
  union { short8 v; bf16 h[8]; } u;
  u.h[0] = __float2bfloat16(a.x); u.h[1] = __float2bfloat16(a.y);
  u.h[2] = __float2bfloat16(a.z); u.h[3] = __float2bfloat16(a.w);
  u.h[4] = __float2bfloat16(b.x); u.h[5] = __float2bfloat16(b.y);
  u.h[6] = __float2bfloat16(b.z); u.h[7] = __float2bfloat16(b.w);
  *((short8*)out + i) = u.v;
}

// ---------------- weight transpose fp32[K][N] -> bf16[N][K] ----------------
__global__ __launch_bounds__(256) void transpose_f2b_kernel(const float* __restrict__ in,
                                                            bf16* __restrict__ out, int K, int N)
{
  int idx = blockIdx.x * 256 + threadIdx.x;
  if (idx >= K * N) return;
  int n = idx / K, k = idx - n * K;
  out[idx] = __float2bfloat16(in[(size_t)k * N + n]);
}

// ---------------- MFMA GEMM: C[M,N] = A[M,K] @ Bt[N,K]^T (+bias) ----------------
// 128x128 tile, BK=32, 4 waves, 4x4 16x16x32 bf16 MFMA per wave.
// 1D grid with bijective XCD swizzle (gridDim.x % 8 == 0): blocks sharing an
// A row-panel are consecutive on one XCD -> A fetched once per XCD group.
// LDS bank swizzle (both-sides, rule #21): 16B slot q at LDS row r holds
// global slot q ^ ((r>>1)&3); fragment read XORs the same -> 2-way (free).
template<typename TC, bool BIAS>
__global__ __launch_bounds__(256) void gemm_mfma(const bf16* __restrict__ A,
                                                 const bf16* __restrict__ Bt,
                                                 const float* __restrict__ bias,
                                                 TC* __restrict__ C,
                                                 int M, int N, int K, int nbx)
{
  __shared__ __align__(16) bf16 As[128 * 32];
  __shared__ __align__(16) bf16 Bs[128 * 32];
  const int tid = threadIdx.x;
  const int wave = tid >> 6, lane = tid & 63;
  const int cpx = gridDim.x >> 3;
  const int wg = (blockIdx.x & 7) * cpx + (blockIdx.x >> 3);
  const int by = wg / nbx, bx = wg - by * nbx;
  const int bm = by * 128, bn = bx * 128;
  const int wr = wave >> 1, wc = wave & 1;

  f32x4 acc[4][4] = {};

  // staging: flat byte F = e*4096 + tid*16 -> LDS row F>>6, slot (F>>4)&3.
  // global source slot is XOR-swizzled so reads can deswizzle.
  const int f0 = tid * 16;
  const int r0 = f0 >> 6, q0 = (f0 >> 4) & 3;
  const int kq0 = q0 ^ ((r0 >> 1) & 3);
  const int f1 = 4096 + tid * 16;
  const int r1 = f1 >> 6, q1 = (f1 >> 4) & 3;
  const int kq1 = q1 ^ ((r1 >> 1) & 3);
  const bf16* a0 = A + (size_t)(bm + r0) * K + kq0 * 8;
  const bf16* a1 = A + (size_t)(bm + r1) * K + kq1 * 8;
  const bf16* b0 = Bt + (size_t)(bn + r0) * K + kq0 * 8;
  const bf16* b1 = Bt + (size_t)(bn + r1) * K + kq1 * 8;
  char* AsW = (char*)As + wave * 1024;   // wave-uniform LDS dest, linear
  char* BsW = (char*)Bs + wave * 1024;

  const int lr = lane & 15, lk = lane >> 4;
  const int qx = lk ^ ((lr >> 1) & 3);   // deswizzled slot (frag-independent)
  const bf16* ArP = As + (size_t)(wr * 64 + lr) * 32 + qx * 8;
  const bf16* BrP = Bs + (size_t)(wc * 64 + lr) * 32 + qx * 8;

  for (int k0 = 0; k0 < K; k0 += 32) {
    GLOAD_LDS16(a0 + k0, AsW);
    GLOAD_LDS16(a1 + k0, AsW + 4096);
    GLOAD_LDS16(b0 + k0, BsW);
    GLOAD_LDS16(b1 + k0, BsW + 4096);
    __syncthreads();
    short8 af[4], bfr[4];
#pragma unroll
    for (int i = 0; i < 4; ++i) af[i]  = *(const short8*)(ArP + i * 512);
#pragma unroll
    for (int j = 0; j < 4; ++j) bfr[j] = *(const short8*)(BrP + j * 512);
#pragma unroll
    for (int i = 0; i < 4; ++i)
#pragma unroll
      for (int j = 0; j < 4; ++j)
        acc[i][j] = __builtin_amdgcn_mfma_f32_16x16x32_bf16(af[i], bfr[j], acc[i][j], 0, 0, 0);
    __syncthreads();
  }

  // epilogue: C/D layout col=lane&15, row=(lane>>4)*4+t
  const int crow = bm + wr * 64 + lk * 4;
  const int ccol = bn + wc * 64 + lr;
#pragma unroll
  for (int j = 0; j < 4; ++j) {
    int col = ccol + j * 16;
    float bv = BIAS ? bias[col] : 0.f;
#pragma unroll
    for (int i = 0; i < 4; ++i)
#pragma unroll
      for (int t = 0; t < 4; ++t) {
        int row = crow + i * 16 + t;
        storeOut(&C[(size_t)row * N + col], acc[i][j][t] + bv);
      }
  }
}

// ---------------- Pooling: mean + max over k x k blocks ----------------
__global__ __launch_bounds__(128) void pool_kernel(const bf16* __restrict__ temp,
                                                   bf16* __restrict__ outp,
                                                   int oh, int ow, int k, int i_scale)
{
  int blk = blockIdx.x;
  int c = threadIdx.x;
  int x = blk % ow; int t = blk / ow;
  int y = t % oh;  t /= oh;
  int b = t % 16;  int s = t / 16;
  float sum = 0.f, mx = -3.4e38f;
  float inv = 1.0f / (float)(k * k);
  for (int dy = 0; dy < k; ++dy)
    for (int dx = 0; dx < k; ++dx) {
      int h = y * k + dy, w = x * k + dx;
      float v = __bfloat162float(temp[((size_t)b * 3136 + h * 56 + w) * 1152 + s * 384 + i_scale * 128 + c]);
      sum += v; mx = fmaxf(mx, v);
    }
  outp[((size_t)(s * 16 + b) * oh * ow + y * ow + x) * 128 + c] = __float2bfloat16(sum * inv + mx);
}

// ---------------- Window attention (4 heads, P=49, hd=32) ----------------
__global__ __launch_bounds__(256) void attn_kernel(
    const bf16* __restrict__ qb, const bf16* __restrict__ kb, const bf16* __restrict__ vb,
    const float* __restrict__ btable, bf16* __restrict__ out,
    int R, int Rw, int ow, int npos,
    long long bstride, int rstride, int out_cstride, int out_coffset)
{
  __shared__ float ks[49][132];
  __shared__ float vs[49][132];
  __shared__ float bs[49][53];
  const int blk = blockIdx.x;
  const int b = blk / R, r = blk % R;
  const int rh = r / Rw, rw = r % Rw;
  const int tid = threadIdx.x;
  const int hb = r & 3;

  for (int idx = tid; idx < 49 * 64; idx += 256) {
    int row = idx >> 6, cp = idx & 63;
    int n = (rh * 7 + row / 7) * ow + (rw * 7 + row % 7);
    size_t base = (size_t)b * bstride + (size_t)n * rstride + cp * 2;
    bf16x2 k2 = *(const bf16x2*)(kb + base);
    bf16x2 v2 = *(const bf16x2*)(vb + base);
    *(float2*)&ks[row][cp * 2] = make_float2(__bfloat162float(k2.x), __bfloat162float(k2.y));
    *(float2*)&vs[row][cp * 2] = make_float2(__bfloat162float(v2.x), __bfloat162float(v2.y));
  }
  for (int idx = tid; idx < 49 * 49; idx += 256) {
    int p = idx / 49, pp = idx % 49;
    int rid = (p / 7 - pp / 7 + 6) * 13 + (p % 7 - pp % 7 + 6);
    bs[p][pp] = btable[rid * 4 + hb];
  }
  __syncthreads();

  if (tid < 196) {
    const int l = tid / 49, p = tid % 49;
    const int n = (rh * 7 + p / 7) * ow + (rw * 7 + p % 7);
    const float scale = 0.17677669529663687f;
    float qreg[32];
    const bf16* qp = qb + (size_t)b * bstride + (size_t)n * rstride + l * 32;
#pragma unroll
    for (int d2 = 0; d2 < 16; ++d2) {
      bf16x2 q2 = *(const bf16x2*)(qp + d2 * 2);
      qreg[d2 * 2 + 0] = __bfloat162float(q2.x) * scale;
      qreg[d2 * 2 + 1] = __bfloat162float(q2.y) * scale;
    }
    float rowv[49];
#pragma unroll
    for (int pp = 0; pp < 49; ++pp) {
      const float* kr = &ks[pp][l * 32];
      float dot = 0.f;
#pragma unroll
      for (int c4 = 0; c4 < 8; ++c4) {
        float4 k4 = *(const float4*)(kr + c4 * 4);
        dot += qreg[c4 * 4 + 0] * k4.x + qreg[c4 * 4 + 1] * k4.y +
               qreg[c4 * 4 + 2] * k4.z + qreg[c4 * 4 + 3] * k4.w;
      }
      rowv[pp] = dot + bs[p][pp];
    }
    float mx = rowv[0];
#pragma unroll
    for (int pp = 1; pp < 49; ++pp) mx = fmaxf(mx, rowv[pp]);
    float sum = 0.f;
#pragma unroll
    for (int pp = 0; pp < 49; ++pp) { rowv[pp] = __expf(rowv[pp] - mx); sum += rowv[pp]; }
    float inv = 1.0f / sum;
    float acc[32] = {};
#pragma unroll
    for (int pp = 0; pp < 49; ++pp) {
      float w = rowv[pp];
      const float* vr = &vs[pp][l * 32];
#pragma unroll
      for (int c4 = 0; c4 < 8; ++c4) {
        float4 v4 = *(const float4*)(vr + c4 * 4);
        acc[c4 * 4 + 0] += w * v4.x; acc[c4 * 4 + 1] += w * v4.y;
        acc[c4 * 4 + 2] += w * v4.z; acc[c4 * 4 + 3] += w * v4.w;
      }
    }
    const int m_out = (l * (R >> 2) + (r >> 2)) * 49 + p;
    const int c0 = (r & 3) * 32;
    bf16* op = out + ((size_t)b * npos + m_out) * out_cstride + out_coffset + c0;
#pragma unroll
    for (int d2 = 0; d2 < 16; ++d2) {
      bf16x2 o2;
      o2.x = __float2bfloat16(acc[d2 * 2 + 0] * inv);
      o2.y = __float2bfloat16(acc[d2 * 2 + 1] * inv);
      *(bf16x2*)(op + d2 * 2) = o2;
    }
  }
}

// ---------------- Bilinear upsample (jax half-pixel, clamped) ----------------
__global__ __launch_bounds__(128) void upsample_kernel(const bf16* __restrict__ ybuf,
                                                       bf16* __restrict__ fused,
                                                       int oh, int ow, int coffset)
{
  int blk = blockIdx.x;
  int c = threadIdx.x;
  int n = blk % 3136, b = blk / 3136;
  int h = n / 56, w = n % 56;
  float ry = (float)oh / 56.f, rx = (float)ow / 56.f;
  float uy = (h + 0.5f) * ry - 0.5f;
  float ux = (w + 0.5f) * rx - 0.5f;
  float fy0 = floorf(uy), fx0 = floorf(ux);
  int y0 = (int)fy0, x0 = (int)fx0;
  float fy = uy - fy0, fx = ux - fx0;
  int y0c = max(y0, 0), y1c = min(y0 + 1, oh - 1);
  int x0c = max(x0, 0), x1c = min(x0 + 1, ow - 1);
  const bf16* base = ybuf + (size_t)b * oh * ow * 128;
  float v00 = __bfloat162float(base[((size_t)y0c * ow + x0c) * 128 + c]);
  float v01 = __bfloat162float(base[((size_t)y0c * ow + x1c) * 128 + c]);
  float v10 = __bfloat162float(base[((size_t)y1c * ow + x0c) * 128 + c]);
  float v11 = __bfloat162float(base[((size_t)y1c * ow + x1c) * 128 + c]);
  float v = (1.f - fy) * ((1.f - fx) * v00 + fx * v01) + fy * ((1.f - fx) * v10 + fx * v11);
  fused[((size_t)b * 3136 + n) * 384 + coffset + c] = __float2bfloat16(v);
}

extern "C" void kernel_launch(void* const* d_in, const int* in_sizes, int n_in,
                              void* d_out, int out_size, void* d_ws, size_t ws_size,
                              hipStream_t stream)
{
  const float* x      = (const float*)d_in[0];
  const float* w_qkv  = (const float*)d_in[1];
  const float* w_proj = (const float*)d_in[2];
  const float* b_proj = (const float*)d_in[3];
  const float* btable = (const float*)d_in[4];

  bf16* temp  = (bf16*)d_ws;                          // 50176 x 1152
  bf16* pool1 = temp  + (size_t)50176 * 1152;         // 3 x 16 x 784 x 128
  bf16* pool2 = pool1 + (size_t)3 * 16 * 784 * 128;   // 3 x 16 x 196 x 128
  bf16* fused = pool2 + (size_t)3 * 16 * 196 * 128;   // 50176 x 384 (also xb)
  bf16* ybuf1 = fused + (size_t)50176 * 384;          // 16 x 784 x 128
  bf16* ybuf2 = ybuf1 + (size_t)16 * 784 * 128;       // 16 x 196 x 128
  bf16* wqkvT = ybuf2 + (size_t)16 * 196 * 128;       // 1152 x 384
  bf16* wprojT= wqkvT + (size_t)1152 * 384;           // 384 x 384
  bf16* xb    = fused;   // x in bf16, dead before attention writes fused

  // 0) dtype prep
  cvt_f32_bf16_kernel<<<(50176 * 384 / 8 + 255) / 256, 256, 0, stream>>>(x, xb, 50176 * 384 / 8);
  transpose_f2b_kernel<<<(1152 * 384 + 255) / 256, 256, 0, stream>>>(w_qkv, wqkvT, 384, 1152);
  transpose_f2b_kernel<<<(384 * 384 + 255) / 256, 256, 0, stream>>>(w_proj, wprojT, 384, 384);

  // 1) QKV projection: temp = xb @ wqkvT^T   (grid 9*392 = 3528, %8==0)
  gemm_mfma<bf16, false><<<3528, 256, 0, stream>>>(
      xb, wqkvT, nullptr, temp, 50176, 1152, 384, 9);

  // 2) pooling for scales 1,2 (mean + max)
  pool_kernel<<<3 * 16 * 28 * 28, 128, 0, stream>>>(temp, pool1, 28, 28, 2, 1);
  pool_kernel<<<3 * 16 * 14 * 14, 128, 0, stream>>>(temp, pool2, 14, 14, 4, 2);

  // 3) window attention per scale
  attn_kernel<<<16 * 64, 256, 0, stream>>>(
      temp, temp + 384, temp + 768, btable, fused,
      64, 8, 56, 3136, (long long)3136 * 1152, 1152, 384, 0);
  attn_kernel<<<16 * 16, 256, 0, stream>>>(
      pool1, pool1 + (size_t)16 * 784 * 128, pool1 + (size_t)2 * 16 * 784 * 128,
      btable, ybuf1, 16, 4, 28, 784, (long long)784 * 128, 128, 128, 0);
  attn_kernel<<<16 * 4, 256, 0, stream>>>(
      pool2, pool2 + (size_t)16 * 196 * 128, pool2 + (size_t)2 * 16 * 196 * 128,
      btable, ybuf2, 4, 2, 14, 196, (long long)196 * 128, 128, 128, 0);

  // 4) bilinear upsample into fused channels [128,256) and [256,384)
  upsample_kernel<<<16 * 3136, 128, 0, stream>>>(ybuf1, fused, 28, 28, 128);
  upsample_kernel<<<16 * 3136, 128, 0, stream>>>(ybuf2, fused, 14, 14, 256);

  // 5) output projection: out = fused @ wprojT^T + b_proj (fp32 out, grid 3*392=1176)
  gemm_mfma<float, true><<<1176, 256, 0, stream>>>(
      fused, wprojT, b_proj, (float*)d_out, 50176, 384, 384, 3);
}

// Round 4
// 278.672 us; speedup vs baseline: 3.4007x; 1.1009x over previous
//
#include <hip/hip_runtime.h>
#include <hip/hip_bf16.h>

typedef __hip_bfloat16 bf16;
typedef __hip_bfloat162 bf16x2;
typedef __attribute__((ext_vector_type(8))) short short8;
typedef __attribute__((ext_vector_type(4))) float f32x4;

__device__ __forceinline__ void storeOut(float* p, float v) { *p = v; }
__device__ __forceinline__ void storeOut(bf16* p, float v) { *p = __float2bfloat16(v); }

#define GLOAD_LDS16(g, l)                                              \
  __builtin_amdgcn_global_load_lds(                                    \
      (const __attribute__((address_space(1))) void*)(g),              \
      (__attribute__((address_space(3))) void*)(l), 16, 0, 0)

// ---------------- fp32 -> bf16 bulk convert (8 elems/thread) ----------------
__global__ __launch_bounds__(256) void cvt_f32_bf16_kernel(const float* __restrict__ in,
                                                           bf16* __restrict__ out, int n8)
{
  int i = blockIdx.x * 256 + threadIdx.x;
  if (i >= n8) return;
  const float4* p = (const float4*)in + (size_t)i * 2;
  float4 a = p[0], b = p[1];
  union { short8 v; bf16 h[8]; } u;
  u.h[0] = __float2bfloat16(a.x); u.h[1] = __float2bfloat16(a.y);
  u.h[2] = __float2bfloat16(a.z); u.h[3] = __float2bfloat16(a.w);
  u.h[4] = __float2bfloat16(b.x); u.h[5] = __float2bfloat16(b.y);
  u.h[6] = __float2bfloat16(b.z); u.h[7] = __float2bfloat16(b.w);
  *((short8*)out + i) = u.v;
}

// ---------------- weight transpose fp32[K][N] -> bf16[N][K] ----------------
__global__ __launch_bounds__(256) void transpose_f2b_kernel(const float* __restrict__ in,
                                                            bf16* __restrict__ out, int K, int N)
{
  int idx = blockIdx.x * 256 + threadIdx.x;
  if (idx >= K * N) return;
  int n = idx / K, k = idx - n * K;
  out[idx] = __float2bfloat16(in[(size_t)k * N + n]);
}

// ---------------- MFMA GEMM: C[M,N] = A[M,K] @ Bt[N,K]^T (+bias) ----------------
// 128x128 tile, BK=64, 4 waves, 4x4x(2 k-slices) 16x16x32 bf16 MFMA per wave.
// 6 K-steps for K=384 -> half the barrier/drain events of BK=32.
// Bank swizzle (both-sides, rule #21): LDS rows are 128B (8 x 16B slots);
// slot q' holds global slot q'^(row&7); reads XOR the same -> even bank spread.
template<typename TC, bool BIAS>
__global__ __launch_bounds__(256) void gemm_mfma(const bf16* __restrict__ A,
                                                 const bf16* __restrict__ Bt,
                                                 const float* __restrict__ bias,
                                                 TC* __restrict__ C,
                                                 int M, int N, int K, int nbx)
{
  __shared__ __align__(16) bf16 As[128 * 64];
  __shared__ __align__(16) bf16 Bs[128 * 64];
  const int tid = threadIdx.x;
  const int wave = tid >> 6, lane = tid & 63;
  const int cpx = gridDim.x >> 3;
  const int wg = (blockIdx.x & 7) * cpx + (blockIdx.x >> 3);
  const int by = wg / nbx, bx = wg - by * nbx;
  const int bm = by * 128, bn = bx * 128;
  const int wr = wave >> 1, wc = wave & 1;

  f32x4 acc[4][4] = {};

  // staging: e in 0..3, flat byte F = e*4096 + tid*16 -> row F>>7, slot (F>>4)&7.
  // global source slot is XOR-swizzled so reads can deswizzle.
  const bf16* aP[4];
  const bf16* bP[4];
#pragma unroll
  for (int e = 0; e < 4; ++e) {
    int flat = e * 4096 + tid * 16;
    int r = flat >> 7;
    int q = ((flat >> 4) & 7) ^ (r & 7);
    aP[e] = A + (size_t)(bm + r) * K + q * 8;
    bP[e] = Bt + (size_t)(bn + r) * K + q * 8;
  }
  char* AsW = (char*)As + wave * 1024;   // wave-uniform LDS dest, linear
  char* BsW = (char*)Bs + wave * 1024;

  const int lr = lane & 15, lk = lane >> 4;
  const int rbA = (wr * 64 + lr) * 64;            // bf16 index of frag row base (A)
  const int rbB = (wc * 64 + lr) * 64;            // (B)
  const int q0 = ((lk    ) ^ (lr & 7)) * 8;       // k-slice 0 deswizzled slot
  const int q1 = ((4 + lk) ^ (lr & 7)) * 8;       // k-slice 1

  for (int k0 = 0; k0 < K; k0 += 64) {
#pragma unroll
    for (int e = 0; e < 4; ++e) GLOAD_LDS16(aP[e] + k0, AsW + e * 4096);
#pragma unroll
    for (int e = 0; e < 4; ++e) GLOAD_LDS16(bP[e] + k0, BsW + e * 4096);
    __syncthreads();
    short8 af0[4], af1[4], bf0[4], bf1[4];
#pragma unroll
    for (int i = 0; i < 4; ++i) {
      af0[i] = *(const short8*)(As + rbA + i * 1024 + q0);
      af1[i] = *(const short8*)(As + rbA + i * 1024 + q1);
    }
#pragma unroll
    for (int j = 0; j < 4; ++j) {
      bf0[j] = *(const short8*)(Bs + rbB + j * 1024 + q0);
      bf1[j] = *(const short8*)(Bs + rbB + j * 1024 + q1);
    }
#pragma unroll
    for (int i = 0; i < 4; ++i)
#pragma unroll
      for (int j = 0; j < 4; ++j) {
        acc[i][j] = __builtin_amdgcn_mfma_f32_16x16x32_bf16(af0[i], bf0[j], acc[i][j], 0, 0, 0);
        acc[i][j] = __builtin_amdgcn_mfma_f32_16x16x32_bf16(af1[i], bf1[j], acc[i][j], 0, 0, 0);
      }
    __syncthreads();
  }

  // epilogue: C/D layout col=lane&15, row=(lane>>4)*4+t
  const int crow = bm + wr * 64 + lk * 4;
  const int ccol = bn + wc * 64 + lr;
#pragma unroll
  for (int j = 0; j < 4; ++j) {
    int col = ccol + j * 16;
    float bv = BIAS ? bias[col] : 0.f;
#pragma unroll
    for (int i = 0; i < 4; ++i)
#pragma unroll
      for (int t = 0; t < 4; ++t) {
        int row = crow + i * 16 + t;
        storeOut(&C[(size_t)row * N + col], acc[i][j][t] + bv);
      }
  }
}

// ---------------- Pooling: mean + max over k x k blocks ----------------
__global__ __launch_bounds__(128) void pool_kernel(const bf16* __restrict__ temp,
                                                   bf16* __restrict__ outp,
                                                   int oh, int ow, int k, int i_scale)
{
  int blk = blockIdx.x;
  int c = threadIdx.x;
  int x = blk % ow; int t = blk / ow;
  int y = t % oh;  t /= oh;
  int b = t % 16;  int s = t / 16;
  float sum = 0.f, mx = -3.4e38f;
  float inv = 1.0f / (float)(k * k);
  for (int dy = 0; dy < k; ++dy)
    for (int dx = 0; dx < k; ++dx) {
      int h = y * k + dy, w = x * k + dx;
      float v = __bfloat162float(temp[((size_t)b * 3136 + h * 56 + w) * 1152 + s * 384 + i_scale * 128 + c]);
      sum += v; mx = fmaxf(mx, v);
    }
  outp[((size_t)(s * 16 + b) * oh * ow + y * ow + x) * 128 + c] = __float2bfloat16(sum * inv + mx);
}

// ---------------- Window attention (4 heads, P=49, hd=32) ----------------
__global__ __launch_bounds__(256) void attn_kernel(
    const bf16* __restrict__ qb, const bf16* __restrict__ kb, const bf16* __restrict__ vb,
    const float* __restrict__ btable, bf16* __restrict__ out,
    int R, int Rw, int ow, int npos,
    long long bstride, int rstride, int out_cstride, int out_coffset)
{
  __shared__ float ks[49][132];
  __shared__ float vs[49][132];
  __shared__ float bs[49][53];
  const int blk = blockIdx.x;
  const int b = blk / R, r = blk % R;
  const int rh = r / Rw, rw = r % Rw;
  const int tid = threadIdx.x;
  const int hb = r & 3;

  for (int idx = tid; idx < 49 * 64; idx += 256) {
    int row = idx >> 6, cp = idx & 63;
    int n = (rh * 7 + row / 7) * ow + (rw * 7 + row % 7);
    size_t base = (size_t)b * bstride + (size_t)n * rstride + cp * 2;
    bf16x2 k2 = *(const bf16x2*)(kb + base);
    bf16x2 v2 = *(const bf16x2*)(vb + base);
    *(float2*)&ks[row][cp * 2] = make_float2(__bfloat162float(k2.x), __bfloat162float(k2.y));
    *(float2*)&vs[row][cp * 2] = make_float2(__bfloat162float(v2.x), __bfloat162float(v2.y));
  }
  for (int idx = tid; idx < 49 * 49; idx += 256) {
    int p = idx / 49, pp = idx % 49;
    int rid = (p / 7 - pp / 7 + 6) * 13 + (p % 7 - pp % 7 + 6);
    bs[p][pp] = btable[rid * 4 + hb];
  }
  __syncthreads();

  if (tid < 196) {
    const int l = tid / 49, p = tid % 49;
    const int n = (rh * 7 + p / 7) * ow + (rw * 7 + p % 7);
    const float scale = 0.17677669529663687f;
    float qreg[32];
    const bf16* qp = qb + (size_t)b * bstride + (size_t)n * rstride + l * 32;
#pragma unroll
    for (int d2 = 0; d2 < 16; ++d2) {
      bf16x2 q2 = *(const bf16x2*)(qp + d2 * 2);
      qreg[d2 * 2 + 0] = __bfloat162float(q2.x) * scale;
      qreg[d2 * 2 + 1] = __bfloat162float(q2.y) * scale;
    }
    float rowv[49];
#pragma unroll
    for (int pp = 0; pp < 49; ++pp) {
      const float* kr = &ks[pp][l * 32];
      float dot = 0.f;
#pragma unroll
      for (int c4 = 0; c4 < 8; ++c4) {
        float4 k4 = *(const float4*)(kr + c4 * 4);
        dot += qreg[c4 * 4 + 0] * k4.x + qreg[c4 * 4 + 1] * k4.y +
               qreg[c4 * 4 + 2] * k4.z + qreg[c4 * 4 + 3] * k4.w;
      }
      rowv[pp] = dot + bs[p][pp];
    }
    float mx = rowv[0];
#pragma unroll
    for (int pp = 1; pp < 49; ++pp) mx = fmaxf(mx, rowv[pp]);
    float sum = 0.f;
#pragma unroll
    for (int pp = 0; pp < 49; ++pp) { rowv[pp] = __expf(rowv[pp] - mx); sum += rowv[pp]; }
    float inv = 1.0f / sum;
    float acc[32] = {};
#pragma unroll
    for (int pp = 0; pp < 49; ++pp) {
      float w = rowv[pp];
      const float* vr = &vs[pp][l * 32];
#pragma unroll
      for (int c4 = 0; c4 < 8; ++c4) {
        float4 v4 = *(const float4*)(vr + c4 * 4);
        acc[c4 * 4 + 0] += w * v4.x; acc[c4 * 4 + 1] += w * v4.y;
        acc[c4 * 4 + 2] += w * v4.z; acc[c4 * 4 + 3] += w * v4.w;
      }
    }
    const int m_out = (l * (R >> 2) + (r >> 2)) * 49 + p;
    const int c0 = (r & 3) * 32;
    bf16* op = out + ((size_t)b * npos + m_out) * out_cstride + out_coffset + c0;
#pragma unroll
    for (int d2 = 0; d2 < 16; ++d2) {
      bf16x2 o2;
      o2.x = __float2bfloat16(acc[d2 * 2 + 0] * inv);
      o2.y = __float2bfloat16(acc[d2 * 2 + 1] * inv);
      *(bf16x2*)(op + d2 * 2) = o2;
    }
  }
}

// ---------------- Fused bilinear upsample for both scales ----------------
// thread -> (pos = b*3136+n, channel-pair cp); writes fused[pos][128+2cp..] and [256+2cp..]
__device__ __forceinline__ float2 bilerp2(const bf16* __restrict__ base, int dim, int h, int w, int cp)
{
  float r = (float)dim / 56.f;
  float uy = (h + 0.5f) * r - 0.5f;
  float ux = (w + 0.5f) * r - 0.5f;
  float fy0 = floorf(uy), fx0 = floorf(ux);
  int y0 = (int)fy0, x0 = (int)fx0;
  float fy = uy - fy0, fx = ux - fx0;
  int y0c = max(y0, 0), y1c = min(y0 + 1, dim - 1);
  int x0c = max(x0, 0), x1c = min(x0 + 1, dim - 1);
  bf16x2 v00 = *(const bf16x2*)(base + ((size_t)y0c * dim + x0c) * 128 + cp * 2);
  bf16x2 v01 = *(const bf16x2*)(base + ((size_t)y0c * dim + x1c) * 128 + cp * 2);
  bf16x2 v10 = *(const bf16x2*)(base + ((size_t)y1c * dim + x0c) * 128 + cp * 2);
  bf16x2 v11 = *(const bf16x2*)(base + ((size_t)y1c * dim + x1c) * 128 + cp * 2);
  float w00 = (1.f - fy) * (1.f - fx), w01 = (1.f - fy) * fx;
  float w10 = fy * (1.f - fx),        w11 = fy * fx;
  float2 o;
  o.x = w00 * __bfloat162float(v00.x) + w01 * __bfloat162float(v01.x) +
        w10 * __bfloat162float(v10.x) + w11 * __bfloat162float(v11.x);
  o.y = w00 * __bfloat162float(v00.y) + w01 * __bfloat162float(v01.y) +
        w10 * __bfloat162float(v10.y) + w11 * __bfloat162float(v11.y);
  return o;
}

__global__ __launch_bounds__(256) void upsample_both_kernel(const bf16* __restrict__ yb1,
                                                            const bf16* __restrict__ yb2,
                                                            bf16* __restrict__ fused)
{
  int t = blockIdx.x * 256 + threadIdx.x;   // over 16*3136*64
  int cp = t & 63;
  int pos = t >> 6;
  int n = pos % 3136, b = pos / 3136;
  int h = n / 56, w = n % 56;
  float2 s1 = bilerp2(yb1 + (size_t)b * 784 * 128, 28, h, w, cp);
  float2 s2 = bilerp2(yb2 + (size_t)b * 196 * 128, 14, h, w, cp);
  bf16* op = fused + (size_t)pos * 384;
  bf16x2 o1; o1.x = __float2bfloat16(s1.x); o1.y = __float2bfloat16(s1.y);
  bf16x2 o2; o2.x = __float2bfloat16(s2.x); o2.y = __float2bfloat16(s2.y);
  *(bf16x2*)(op + 128 + cp * 2) = o1;
  *(bf16x2*)(op + 256 + cp * 2) = o2;
}

extern "C" void kernel_launch(void* const* d_in, const int* in_sizes, int n_in,
                              void* d_out, int out_size, void* d_ws, size_t ws_size,
                              hipStream_t stream)
{
  const float* x      = (const float*)d_in[0];
  const float* w_qkv  = (const float*)d_in[1];
  const float* w_proj = (const float*)d_in[2];
  const float* b_proj = (const float*)d_in[3];
  const float* btable = (const float*)d_in[4];

  bf16* temp  = (bf16*)d_ws;                          // 50176 x 1152
  bf16* pool1 = temp  + (size_t)50176 * 1152;         // 3 x 16 x 784 x 128
  bf16* pool2 = pool1 + (size_t)3 * 16 * 784 * 128;   // 3 x 16 x 196 x 128
  bf16* fused = pool2 + (size_t)3 * 16 * 196 * 128;   // 50176 x 384 (also xb)
  bf16* ybuf1 = fused + (size_t)50176 * 384;          // 16 x 784 x 128
  bf16* ybuf2 = ybuf1 + (size_t)16 * 784 * 128;       // 16 x 196 x 128
  bf16* wqkvT = ybuf2 + (size_t)16 * 196 * 128;       // 1152 x 384
  bf16* wprojT= wqkvT + (size_t)1152 * 384;           // 384 x 384
  bf16* xb    = fused;   // x in bf16, dead before attention writes fused

  // 0) dtype prep
  cvt_f32_bf16_kernel<<<(50176 * 384 / 8 + 255) / 256, 256, 0, stream>>>(x, xb, 50176 * 384 / 8);
  transpose_f2b_kernel<<<(1152 * 384 + 255) / 256, 256, 0, stream>>>(w_qkv, wqkvT, 384, 1152);
  transpose_f2b_kernel<<<(384 * 384 + 255) / 256, 256, 0, stream>>>(w_proj, wprojT, 384, 384);

  // 1) QKV projection: temp = xb @ wqkvT^T   (grid 9*392 = 3528, %8==0)
  gemm_mfma<bf16, false><<<3528, 256, 0, stream>>>(
      xb, wqkvT, nullptr, temp, 50176, 1152, 384, 9);

  // 2) pooling for scales 1,2 (mean + max)
  pool_kernel<<<3 * 16 * 28 * 28, 128, 0, stream>>>(temp, pool1, 28, 28, 2, 1);
  pool_kernel<<<3 * 16 * 14 * 14, 128, 0, stream>>>(temp, pool2, 14, 14, 4, 2);

  // 3) window attention per scale
  attn_kernel<<<16 * 64, 256, 0, stream>>>(
      temp, temp + 384, temp + 768, btable, fused,
      64, 8, 56, 3136, (long long)3136 * 1152, 1152, 384, 0);
  attn_kernel<<<16 * 16, 256, 0, stream>>>(
      pool1, pool1 + (size_t)16 * 784 * 128, pool1 + (size_t)2 * 16 * 784 * 128,
      btable, ybuf1, 16, 4, 28, 784, (long long)784 * 128, 128, 128, 0);
  attn_kernel<<<16 * 4, 256, 0, stream>>>(
      pool2, pool2 + (size_t)16 * 196 * 128, pool2 + (size_t)2 * 16 * 196 * 128,
      btable, ybuf2, 4, 2, 14, 196, (long long)196 * 128, 128, 128, 0);

  // 4) fused bilinear upsample into fused channels [128,256) and [256,384)
  upsample_both_kernel<<<16 * 3136 * 64 / 256, 256, 0, stream>>>(ybuf1, ybuf2, fused);

  // 5) output projection: out = fused @ wprojT^T + b_proj (fp32 out, grid 3*392=1176)
  gemm_mfma<float, true><<<1176, 256, 0, stream>>>(
      fused, wprojT, b_proj, (float*)d_out, 50176, 384, 384, 3);
}

// Round 5
// 243.268 us; speedup vs baseline: 3.8956x; 1.1455x over previous
//
#include <hip/hip_runtime.h>
#include <hip/hip_bf16.h>

typedef __hip_bfloat16 bf16;
typedef __hip_bfloat162 bf16x2;
typedef __attribute__((ext_vector_type(8))) short short8;
typedef __attribute__((ext_vector_type(4))) float f32x4;

__device__ __forceinline__ void storeOut(float* p, float v) { *p = v; }
__device__ __forceinline__ void storeOut(bf16* p, float v) { *p = __float2bfloat16(v); }

#define GLOAD_LDS16(g, l)                                              \
  __builtin_amdgcn_global_load_lds(                                    \
      (const __attribute__((address_space(1))) void*)(g),              \
      (__attribute__((address_space(3))) void*)(l), 16, 0, 0)

// ---------------- fp32 -> bf16 bulk convert (8 elems/thread) ----------------
__global__ __launch_bounds__(256) void cvt_f32_bf16_kernel(const float* __restrict__ in,
                                                           bf16* __restrict__ out, int n8)
{
  int i = blockIdx.x * 256 + threadIdx.x;
  if (i >= n8) return;
  const float4* p = (const float4*)in + (size_t)i * 2;
  float4 a = p[0], b = p[1];
  union { short8 v; bf16 h[8]; } u;
  u.h[0] = __float2bfloat16(a.x); u.h[1] = __float2bfloat16(a.y);
  u.h[2] = __float2bfloat16(a.z); u.h[3] = __float2bfloat16(a.w);
  u.h[4] = __float2bfloat16(b.x); u.h[5] = __float2bfloat16(b.y);
  u.h[6] = __float2bfloat16(b.z); u.h[7] = __float2bfloat16(b.w);
  *((short8*)out + i) = u.v;
}

// ---------------- both weight transposes fp32[K][N] -> bf16[N][K] ----------------
__global__ __launch_bounds__(256) void transpose2_kernel(const float* __restrict__ w_qkv,
                                                         const float* __restrict__ w_proj,
                                                         bf16* __restrict__ wqkvT,
                                                         bf16* __restrict__ wprojT)
{
  int idx = blockIdx.x * 256 + threadIdx.x;
  if (idx < 1152 * 384) {
    int n = idx / 384, k = idx - n * 384;
    wqkvT[idx] = __float2bfloat16(w_qkv[(size_t)k * 1152 + n]);
  } else {
    idx -= 1152 * 384;
    int n = idx / 384, k = idx - n * 384;
    wprojT[idx] = __float2bfloat16(w_proj[(size_t)k * 384 + n]);
  }
}

// ---------------- MFMA GEMM: C[M,N] = A[M,K] @ Bt[N,K]^T (+bias) ----------------
// 128x128 tile, BK=64, 4 waves, double-buffered LDS (T3 minimum 2-phase):
//   [sync] -> issue STAGE(next) -> ds_read+MFMA(cur) -> loop
// One barrier per K-step; the vmcnt(0) drain at the barrier lands after the
// loads had the whole MFMA phase in flight.
// Bank swizzle (both-sides, rule #21): LDS rows are 128B (8 x 16B slots);
// slot q' holds global slot q'^(row&7); reads XOR the same.
template<typename TC, bool BIAS>
__global__ __launch_bounds__(256) void gemm_mfma(const bf16* __restrict__ A,
                                                 const bf16* __restrict__ Bt,
                                                 const float* __restrict__ bias,
                                                 TC* __restrict__ C,
                                                 int M, int N, int K, int nbx)
{
  __shared__ __align__(16) bf16 As[2][128 * 64];
  __shared__ __align__(16) bf16 Bs[2][128 * 64];
  const int tid = threadIdx.x;
  const int wave = tid >> 6, lane = tid & 63;
  const int cpx = gridDim.x >> 3;
  const int wg = (blockIdx.x & 7) * cpx + (blockIdx.x >> 3);
  const int by = wg / nbx, bx = wg - by * nbx;
  const int bm = by * 128, bn = bx * 128;
  const int wr = wave >> 1, wc = wave & 1;

  f32x4 acc[4][4] = {};

  // staging: e in 0..3, flat byte F = e*4096 + tid*16 -> row F>>7, slot (F>>4)&7.
  // global source slot is XOR-swizzled so reads can deswizzle.
  const bf16* aP[4];
  const bf16* bP[4];
#pragma unroll
  for (int e = 0; e < 4; ++e) {
    int flat = e * 4096 + tid * 16;
    int r = flat >> 7;
    int q = ((flat >> 4) & 7) ^ (r & 7);
    aP[e] = A + (size_t)(bm + r) * K + q * 8;
    bP[e] = Bt + (size_t)(bn + r) * K + q * 8;
  }

  auto STAGE = [&](int buf, int k0) {
    char* aw = (char*)(&As[buf][0]) + wave * 1024;   // wave-uniform dest, linear
    char* bw = (char*)(&Bs[buf][0]) + wave * 1024;
#pragma unroll
    for (int e = 0; e < 4; ++e) {
      GLOAD_LDS16(aP[e] + k0, aw + e * 4096);
      GLOAD_LDS16(bP[e] + k0, bw + e * 4096);
    }
  };

  const int lr = lane & 15, lk = lane >> 4;
  const int rbA = (wr * 64 + lr) * 64;            // bf16 index of frag row base (A)
  const int rbB = (wc * 64 + lr) * 64;            // (B)
  const int q0 = ((lk    ) ^ (lr & 7)) * 8;       // k-slice 0 deswizzled slot
  const int q1 = ((4 + lk) ^ (lr & 7)) * 8;       // k-slice 1

  const int nt = K >> 6;
  STAGE(0, 0);
  int cur = 0;
  for (int t = 0; t < nt; ++t) {
    __syncthreads();                      // drains stage of As[cur]/Bs[cur]
    if (t + 1 < nt) STAGE(cur ^ 1, (t + 1) << 6);   // fly during compute
    const bf16* Ab = &As[cur][0];
    const bf16* Bb = &Bs[cur][0];
    short8 af0[4], af1[4], bf0[4], bf1[4];
#pragma unroll
    for (int i = 0; i < 4; ++i) {
      af0[i] = *(const short8*)(Ab + rbA + i * 1024 + q0);
      af1[i] = *(const short8*)(Ab + rbA + i * 1024 + q1);
    }
#pragma unroll
    for (int j = 0; j < 4; ++j) {
      bf0[j] = *(const short8*)(Bb + rbB + j * 1024 + q0);
      bf1[j] = *(const short8*)(Bb + rbB + j * 1024 + q1);
    }
#pragma unroll
    for (int i = 0; i < 4; ++i)
#pragma unroll
      for (int j = 0; j < 4; ++j) {
        acc[i][j] = __builtin_amdgcn_mfma_f32_16x16x32_bf16(af0[i], bf0[j], acc[i][j], 0, 0, 0);
        acc[i][j] = __builtin_amdgcn_mfma_f32_16x16x32_bf16(af1[i], bf1[j], acc[i][j], 0, 0, 0);
      }
    cur ^= 1;
  }

  // epilogue: C/D layout col=lane&15, row=(lane>>4)*4+t
  const int crow = bm + wr * 64 + lk * 4;
  const int ccol = bn + wc * 64 + lr;
#pragma unroll
  for (int j = 0; j < 4; ++j) {
    int col = ccol + j * 16;
    float bv = BIAS ? bias[col] : 0.f;
#pragma unroll
    for (int i = 0; i < 4; ++i)
#pragma unroll
      for (int t = 0; t < 4; ++t) {
        int row = crow + i * 16 + t;
        storeOut(&C[(size_t)row * N + col], acc[i][j][t] + bv);
      }
  }
}

// ---------------- Pooling (both scales): mean + max over k x k blocks ----------------
__global__ __launch_bounds__(128) void pool_both_kernel(const bf16* __restrict__ temp,
                                                        bf16* __restrict__ pool1,
                                                        bf16* __restrict__ pool2)
{
  int blk = blockIdx.x;
  bf16* outp; int oh, k, isc;
  if (blk < 3 * 16 * 28 * 28) { outp = pool1; oh = 28; k = 2; isc = 1; }
  else { blk -= 3 * 16 * 28 * 28; outp = pool2; oh = 14; k = 4; isc = 2; }
  const int ow = oh;
  int c = threadIdx.x;
  int x = blk % ow; int t = blk / ow;
  int y = t % oh;  t /= oh;
  int b = t % 16;  int s = t / 16;
  float sum = 0.f, mx = -3.4e38f;
  float inv = 1.0f / (float)(k * k);
  for (int dy = 0; dy < k; ++dy)
    for (int dx = 0; dx < k; ++dx) {
      int h = y * k + dy, w = x * k + dx;
      float v = __bfloat162float(temp[((size_t)b * 3136 + h * 56 + w) * 1152 + s * 384 + isc * 128 + c]);
      sum += v; mx = fmaxf(mx, v);
    }
  outp[((size_t)(s * 16 + b) * oh * ow + y * ow + x) * 128 + c] = __float2bfloat16(sum * inv + mx);
}

// ---------------- Window attention, all 3 scales in one launch ----------------
struct AttnP {
  const bf16 *qb, *kb, *vb;
  bf16* out;
  int R, Rw, ow, npos, rstride, out_cstride, out_coffset, blk0;
  long long bstride;
};

__global__ __launch_bounds__(256) void attn_kernel(AttnP P0, AttnP P1, AttnP P2)
{
  __shared__ float ks[49][132];
  __shared__ float vs[49][132];
  __shared__ float bs[49][53];
  const AttnP p = (blockIdx.x >= (unsigned)P2.blk0) ? P2
                : (blockIdx.x >= (unsigned)P1.blk0) ? P1 : P0;
  const int blk = blockIdx.x - p.blk0;
  const int b = blk / p.R, r = blk % p.R;
  const int rh = r / p.Rw, rw = r % p.Rw;
  const int tid = threadIdx.x;
  const int hb = r & 3;
  const float* btable = (const float*)p.qb;  // unused placeholder (set below)

  // NOTE: bias table passed via P0/P1/P2 would bloat struct; use global pointer param trick:
  // we instead smuggle it through P0.out? No — keep it simple: btable is a separate
  // __constant__-like arg; see wrapper below. (This line is replaced by real param.)
  (void)btable;
  // real code continues in attn_body
  // -- inlined below --
  extern __shared__ char _dummy[]; (void)_dummy;
  // (body uses p + gbias)
  // This placeholder never executes; actual kernel is attn_kernel3 below.
}

// Clean version with explicit bias param:
__global__ __launch_bounds__(256) void attn_kernel3(const float* __restrict__ btable,
                                                    AttnP P0, AttnP P1, AttnP P2)
{
  __shared__ float ks[49][132];
  __shared__ float vs[49][132];
  __shared__ float bs[49][53];
  const AttnP p = (blockIdx.x >= (unsigned)P2.blk0) ? P2
                : (blockIdx.x >= (unsigned)P1.blk0) ? P1 : P0;
  const int blk = blockIdx.x - p.blk0;
  const int b = blk / p.R, r = blk % p.R;
  const int rh = r / p.Rw, rw = r % p.Rw;
  const int tid = threadIdx.x;
  const int hb = r & 3;

  for (int idx = tid; idx < 49 * 64; idx += 256) {
    int row = idx >> 6, cp = idx & 63;
    int n = (rh * 7 + row / 7) * p.ow + (rw * 7 + row % 7);
    size_t base = (size_t)b * p.bstride + (size_t)n * p.rstride + cp * 2;
    bf16x2 k2 = *(const bf16x2*)(p.kb + base);
    bf16x2 v2 = *(const bf16x2*)(p.vb + base);
    *(float2*)&ks[row][cp * 2] = make_float2(__bfloat162float(k2.x), __bfloat162float(k2.y));
    *(float2*)&vs[row][cp * 2] = make_float2(__bfloat162float(v2.x), __bfloat162float(v2.y));
  }
  for (int idx = tid; idx < 49 * 49; idx += 256) {
    int pq = idx / 49, pp = idx % 49;
    int rid = (pq / 7 - pp / 7 + 6) * 13 + (pq % 7 - pp % 7 + 6);
    bs[pq][pp] = btable[rid * 4 + hb];
  }
  __syncthreads();

  if (tid < 196) {
    const int l = tid / 49, pq = tid % 49;
    const int n = (rh * 7 + pq / 7) * p.ow + (rw * 7 + pq % 7);
    const float scale = 0.17677669529663687f;
    float qreg[32];
    const bf16* qp = p.qb + (size_t)b * p.bstride + (size_t)n * p.rstride + l * 32;
#pragma unroll
    for (int d2 = 0; d2 < 16; ++d2) {
      bf16x2 q2 = *(const bf16x2*)(qp + d2 * 2);
      qreg[d2 * 2 + 0] = __bfloat162float(q2.x) * scale;
      qreg[d2 * 2 + 1] = __bfloat162float(q2.y) * scale;
    }
    float rowv[49];
#pragma unroll
    for (int pp = 0; pp < 49; ++pp) {
      const float* kr = &ks[pp][l * 32];
      float dot = 0.f;
#pragma unroll
      for (int c4 = 0; c4 < 8; ++c4) {
        float4 k4 = *(const float4*)(kr + c4 * 4);
        dot += qreg[c4 * 4 + 0] * k4.x + qreg[c4 * 4 + 1] * k4.y +
               qreg[c4 * 4 + 2] * k4.z + qreg[c4 * 4 + 3] * k4.w;
      }
      rowv[pp] = dot + bs[pq][pp];
    }
    float mx = rowv[0];
#pragma unroll
    for (int pp = 1; pp < 49; ++pp) mx = fmaxf(mx, rowv[pp]);
    float sum = 0.f;
#pragma unroll
    for (int pp = 0; pp < 49; ++pp) { rowv[pp] = __expf(rowv[pp] - mx); sum += rowv[pp]; }
    float inv = 1.0f / sum;
    float acc[32] = {};
#pragma unroll
    for (int pp = 0; pp < 49; ++pp) {
      float w = rowv[pp];
      const float* vr = &vs[pp][l * 32];
#pragma unroll
      for (int c4 = 0; c4 < 8; ++c4) {
        float4 v4 = *(const float4*)(vr + c4 * 4);
        acc[c4 * 4 + 0] += w * v4.x; acc[c4 * 4 + 1] += w * v4.y;
        acc[c4 * 4 + 2] += w * v4.z; acc[c4 * 4 + 3] += w * v4.w;
      }
    }
    const int m_out = (l * (p.R >> 2) + (r >> 2)) * 49 + pq;
    const int c0 = (r & 3) * 32;
    bf16* op = p.out + ((size_t)b * p.npos + m_out) * p.out_cstride + p.out_coffset + c0;
#pragma unroll
    for (int d2 = 0; d2 < 16; ++d2) {
      bf16x2 o2;
      o2.x = __float2bfloat16(acc[d2 * 2 + 0] * inv);
      o2.y = __float2bfloat16(acc[d2 * 2 + 1] * inv);
      *(bf16x2*)(op + d2 * 2) = o2;
    }
  }
}

// ---------------- Fused bilinear upsample for both scales ----------------
__device__ __forceinline__ float2 bilerp2(const bf16* __restrict__ base, int dim, int h, int w, int cp)
{
  float r = (float)dim / 56.f;
  float uy = (h + 0.5f) * r - 0.5f;
  float ux = (w + 0.5f) * r - 0.5f;
  float fy0 = floorf(uy), fx0 = floorf(ux);
  int y0 = (int)fy0, x0 = (int)fx0;
  float fy = uy - fy0, fx = ux - fx0;
  int y0c = max(y0, 0), y1c = min(y0 + 1, dim - 1);
  int x0c = max(x0, 0), x1c = min(x0 + 1, dim - 1);
  bf16x2 v00 = *(const bf16x2*)(base + ((size_t)y0c * dim + x0c) * 128 + cp * 2);
  bf16x2 v01 = *(const bf16x2*)(base + ((size_t)y0c * dim + x1c) * 128 + cp * 2);
  bf16x2 v10 = *(const bf16x2*)(base + ((size_t)y1c * dim + x0c) * 128 + cp * 2);
  bf16x2 v11 = *(const bf16x2*)(base + ((size_t)y1c * dim + x1c) * 128 + cp * 2);
  float w00 = (1.f - fy) * (1.f - fx), w01 = (1.f - fy) * fx;
  float w10 = fy * (1.f - fx),        w11 = fy * fx;
  float2 o;
  o.x = w00 * __bfloat162float(v00.x) + w01 * __bfloat162float(v01.x) +
        w10 * __bfloat162float(v10.x) + w11 * __bfloat162float(v11.x);
  o.y = w00 * __bfloat162float(v00.y) + w01 * __bfloat162float(v01.y) +
        w10 * __bfloat162float(v10.y) + w11 * __bfloat162float(v11.y);
  return o;
}

__global__ __launch_bounds__(256) void upsample_both_kernel(const bf16* __restrict__ yb1,
                                                            const bf16* __restrict__ yb2,
                                                            bf16* __restrict__ fused)
{
  int t = blockIdx.x * 256 + threadIdx.x;   // over 16*3136*64
  int cp = t & 63;
  int pos = t >> 6;
  int n = pos % 3136, b = pos / 3136;
  int h = n / 56, w = n % 56;
  float2 s1 = bilerp2(yb1 + (size_t)b * 784 * 128, 28, h, w, cp);
  float2 s2 = bilerp2(yb2 + (size_t)b * 196 * 128, 14, h, w, cp);
  bf16* op = fused + (size_t)pos * 384;
  bf16x2 o1; o1.x = __float2bfloat16(s1.x); o1.y = __float2bfloat16(s1.y);
  bf16x2 o2; o2.x = __float2bfloat16(s2.x); o2.y = __float2bfloat16(s2.y);
  *(bf16x2*)(op + 128 + cp * 2) = o1;
  *(bf16x2*)(op + 256 + cp * 2) = o2;
}

extern "C" void kernel_launch(void* const* d_in, const int* in_sizes, int n_in,
                              void* d_out, int out_size, void* d_ws, size_t ws_size,
                              hipStream_t stream)
{
  const float* x      = (const float*)d_in[0];
  const float* w_qkv  = (const float*)d_in[1];
  const float* w_proj = (const float*)d_in[2];
  const float* b_proj = (const float*)d_in[3];
  const float* btable = (const float*)d_in[4];

  bf16* temp  = (bf16*)d_ws;                          // 50176 x 1152
  bf16* pool1 = temp  + (size_t)50176 * 1152;         // 3 x 16 x 784 x 128
  bf16* pool2 = pool1 + (size_t)3 * 16 * 784 * 128;   // 3 x 16 x 196 x 128
  bf16* fused = pool2 + (size_t)3 * 16 * 196 * 128;   // 50176 x 384 (also xb)
  bf16* ybuf1 = fused + (size_t)50176 * 384;          // 16 x 784 x 128
  bf16* ybuf2 = ybuf1 + (size_t)16 * 784 * 128;       // 16 x 196 x 128
  bf16* wqkvT = ybuf2 + (size_t)16 * 196 * 128;       // 1152 x 384
  bf16* wprojT= wqkvT + (size_t)1152 * 384;           // 384 x 384
  bf16* xb    = fused;   // x in bf16, dead before attention writes fused

  // 0) dtype prep
  cvt_f32_bf16_kernel<<<(50176 * 384 / 8 + 255) / 256, 256, 0, stream>>>(x, xb, 50176 * 384 / 8);
  transpose2_kernel<<<(1152 * 384 + 384 * 384) / 256, 256, 0, stream>>>(w_qkv, w_proj, wqkvT, wprojT);

  // 1) QKV projection: temp = xb @ wqkvT^T   (grid 9*392 = 3528, %8==0)
  gemm_mfma<bf16, false><<<3528, 256, 0, stream>>>(
      xb, wqkvT, nullptr, temp, 50176, 1152, 384, 9);

  // 2) pooling for scales 1,2 (mean + max), one launch
  pool_both_kernel<<<3 * 16 * 28 * 28 + 3 * 16 * 14 * 14, 128, 0, stream>>>(temp, pool1, pool2);

  // 3) window attention, all scales in one launch
  AttnP P0{temp, temp + 384, temp + 768, fused,
           64, 8, 56, 3136, 1152, 384, 0, 0, (long long)3136 * 1152};
  AttnP P1{pool1, pool1 + (size_t)16 * 784 * 128, pool1 + (size_t)2 * 16 * 784 * 128, ybuf1,
           16, 4, 28, 784, 128, 128, 0, 1024, (long long)784 * 128};
  AttnP P2{pool2, pool2 + (size_t)16 * 196 * 128, pool2 + (size_t)2 * 16 * 196 * 128, ybuf2,
           4, 2, 14, 196, 128, 128, 0, 1280, (long long)196 * 128};
  attn_kernel3<<<1344, 256, 0, stream>>>(btable, P0, P1, P2);

  // 4) fused bilinear upsample into fused channels [128,256) and [256,384)
  upsample_both_kernel<<<16 * 3136 * 64 / 256, 256, 0, stream>>>(ybuf1, ybuf2, fused);

  // 5) output projection: out = fused @ wprojT^T + b_proj (fp32 out, grid 3*392=1176)
  gemm_mfma<float, true><<<1176, 256, 0, stream>>>(
      fused, wprojT, b_proj, (float*)d_out, 50176, 384, 384, 3);
}

// Round 7
// 210.191 us; speedup vs baseline: 4.5087x; 1.1574x over previous
//
#include <hip/hip_runtime.h>
#include <hip/hip_bf16.h>

typedef __hip_bfloat16 bf16;
typedef __hip_bfloat162 bf16x2;
typedef __attribute__((ext_vector_type(8))) short short8;
typedef __attribute__((ext_vector_type(4))) float f32x4;

__device__ __forceinline__ void storeOut(float* p, float v) { *p = v; }
__device__ __forceinline__ void storeOut(bf16* p, float v) { *p = __float2bfloat16(v); }

#define GLOAD_LDS16(g, l)                                              \
  __builtin_amdgcn_global_load_lds(                                    \
      (const __attribute__((address_space(1))) void*)(g),              \
      (__attribute__((address_space(3))) void*)(l), 16, 0, 0)

// ---------------- fp32 -> bf16 bulk convert (8 elems/thread) ----------------
__global__ __launch_bounds__(256) void cvt_f32_bf16_kernel(const float* __restrict__ in,
                                                           bf16* __restrict__ out, int n8)
{
  int i = blockIdx.x * 256 + threadIdx.x;
  if (i >= n8) return;
  const float4* p = (const float4*)in + (size_t)i * 2;
  float4 a = p[0], b = p[1];
  union { short8 v; bf16 h[8]; } u;
  u.h[0] = __float2bfloat16(a.x); u.h[1] = __float2bfloat16(a.y);
  u.h[2] = __float2bfloat16(a.z); u.h[3] = __float2bfloat16(a.w);
  u.h[4] = __float2bfloat16(b.x); u.h[5] = __float2bfloat16(b.y);
  u.h[6] = __float2bfloat16(b.z); u.h[7] = __float2bfloat16(b.w);
  *((short8*)out + i) = u.v;
}

// ---------------- both weight transposes fp32[K][N] -> bf16[N][K] ----------------
__global__ __launch_bounds__(256) void transpose2_kernel(const float* __restrict__ w_qkv,
                                                         const float* __restrict__ w_proj,
                                                         bf16* __restrict__ wqkvT,
                                                         bf16* __restrict__ wprojT)
{
  int idx = blockIdx.x * 256 + threadIdx.x;
  if (idx < 1152 * 384) {
    int n = idx / 384, k = idx - n * 384;
    wqkvT[idx] = __float2bfloat16(w_qkv[(size_t)k * 1152 + n]);
  } else {
    idx -= 1152 * 384;
    int n = idx / 384, k = idx - n * 384;
    wprojT[idx] = __float2bfloat16(w_proj[(size_t)k * 384 + n]);
  }
}

// ---------------- MFMA GEMM (unchanged; verified) ----------------
template<typename TC, bool BIAS>
__global__ __launch_bounds__(256) void gemm_mfma(const bf16* __restrict__ A,
                                                 const bf16* __restrict__ Bt,
                                                 const float* __restrict__ bias,
                                                 TC* __restrict__ C,
                                                 int M, int N, int K, int nbx)
{
  __shared__ __align__(16) bf16 As[2][128 * 64];
  __shared__ __align__(16) bf16 Bs[2][128 * 64];
  const int tid = threadIdx.x;
  const int wave = tid >> 6, lane = tid & 63;
  const int cpx = gridDim.x >> 3;
  const int wg = (blockIdx.x & 7) * cpx + (blockIdx.x >> 3);
  const int by = wg / nbx, bx = wg - by * nbx;
  const int bm = by * 128, bn = bx * 128;
  const int wr = wave >> 1, wc = wave & 1;

  f32x4 acc[4][4] = {};

  const bf16* aP[4];
  const bf16* bP[4];
#pragma unroll
  for (int e = 0; e < 4; ++e) {
    int flat = e * 4096 + tid * 16;
    int r = flat >> 7;
    int q = ((flat >> 4) & 7) ^ (r & 7);
    aP[e] = A + (size_t)(bm + r) * K + q * 8;
    bP[e] = Bt + (size_t)(bn + r) * K + q * 8;
  }

  auto STAGE = [&](int buf, int k0) {
    char* aw = (char*)(&As[buf][0]) + wave * 1024;
    char* bw = (char*)(&Bs[buf][0]) + wave * 1024;
#pragma unroll
    for (int e = 0; e < 4; ++e) {
      GLOAD_LDS16(aP[e] + k0, aw + e * 4096);
      GLOAD_LDS16(bP[e] + k0, bw + e * 4096);
    }
  };

  const int lr = lane & 15, lk = lane >> 4;
  const int rbA = (wr * 64 + lr) * 64;
  const int rbB = (wc * 64 + lr) * 64;
  const int q0 = ((lk    ) ^ (lr & 7)) * 8;
  const int q1 = ((4 + lk) ^ (lr & 7)) * 8;

  const int nt = K >> 6;
  STAGE(0, 0);
  int cur = 0;
  for (int t = 0; t < nt; ++t) {
    __syncthreads();
    if (t + 1 < nt) STAGE(cur ^ 1, (t + 1) << 6);
    const bf16* Ab = &As[cur][0];
    const bf16* Bb = &Bs[cur][0];
    short8 af0[4], af1[4], bf0[4], bf1[4];
#pragma unroll
    for (int i = 0; i < 4; ++i) {
      af0[i] = *(const short8*)(Ab + rbA + i * 1024 + q0);
      af1[i] = *(const short8*)(Ab + rbA + i * 1024 + q1);
    }
#pragma unroll
    for (int j = 0; j < 4; ++j) {
      bf0[j] = *(const short8*)(Bb + rbB + j * 1024 + q0);
      bf1[j] = *(const short8*)(Bb + rbB + j * 1024 + q1);
    }
#pragma unroll
    for (int i = 0; i < 4; ++i)
#pragma unroll
      for (int j = 0; j < 4; ++j) {
        acc[i][j] = __builtin_amdgcn_mfma_f32_16x16x32_bf16(af0[i], bf0[j], acc[i][j], 0, 0, 0);
        acc[i][j] = __builtin_amdgcn_mfma_f32_16x16x32_bf16(af1[i], bf1[j], acc[i][j], 0, 0, 0);
      }
    cur ^= 1;
  }

  const int crow = bm + wr * 64 + lk * 4;
  const int ccol = bn + wc * 64 + lr;
#pragma unroll
  for (int j = 0; j < 4; ++j) {
    int col = ccol + j * 16;
    float bv = BIAS ? bias[col] : 0.f;
#pragma unroll
    for (int i = 0; i < 4; ++i)
#pragma unroll
      for (int t = 0; t < 4; ++t) {
        int row = crow + i * 16 + t;
        storeOut(&C[(size_t)row * N + col], acc[i][j][t] + bv);
      }
  }
}

// ---------------- Pooling (both scales): mean + max ----------------
__global__ __launch_bounds__(128) void pool_both_kernel(const bf16* __restrict__ temp,
                                                        bf16* __restrict__ pool1,
                                                        bf16* __restrict__ pool2)
{
  int blk = blockIdx.x;
  bf16* outp; int oh, k, isc;
  if (blk < 3 * 16 * 28 * 28) { outp = pool1; oh = 28; k = 2; isc = 1; }
  else { blk -= 3 * 16 * 28 * 28; outp = pool2; oh = 14; k = 4; isc = 2; }
  const int ow = oh;
  int c = threadIdx.x;
  int x = blk % ow; int t = blk / ow;
  int y = t % oh;  t /= oh;
  int b = t % 16;  int s = t / 16;
  float sum = 0.f, mx = -3.4e38f;
  float inv = 1.0f / (float)(k * k);
  for (int dy = 0; dy < k; ++dy)
    for (int dx = 0; dx < k; ++dx) {
      int h = y * k + dy, w = x * k + dx;
      float v = __bfloat162float(temp[((size_t)b * 3136 + h * 56 + w) * 1152 + s * 384 + isc * 128 + c]);
      sum += v; mx = fmaxf(mx, v);
    }
  outp[((size_t)(s * 16 + b) * oh * ow + y * ow + x) * 128 + c] = __float2bfloat16(sum * inv + mx);
}

// ---------------- MFMA window attention, all 3 scales in one launch ----------------
// Block = one window; 4 waves = 4 heads. P=49 padded to 64.
// Per-head LDS strides (bf16 elements): Kls 64*40=2560, Vt 32*64=2048, Pls 64*64=4096.
struct AttnP {
  const bf16 *qb, *kb, *vb;
  bf16* out;
  int R, Rw, ow, npos, rstride, out_cstride, out_coffset, blk0;
  long long bstride;
};

__global__ __launch_bounds__(256) void attn_mfma(const float* __restrict__ btable,
                                                 AttnP P0, AttnP P1, AttnP P2)
{
  __shared__ __align__(16) bf16 Kls[4 * 64 * 40];  // [h][row][32+8pad], rows>=49 stale (masked)
  __shared__ __align__(16) bf16 Vt[4 * 32 * 64];   // [h][d][pp] swizzled, pp>=49 zeroed
  __shared__ __align__(16) bf16 Pls[4 * 64 * 64];  // [h][p][pp] swizzled
  __shared__ float bias_s[169];

  const AttnP p = (blockIdx.x >= (unsigned)P2.blk0) ? P2
                : (blockIdx.x >= (unsigned)P1.blk0) ? P1 : P0;
  const int blk = blockIdx.x - p.blk0;
  const int b = blk / p.R, r = blk % p.R;
  const int rh = r / p.Rw, rw = r % p.Rw;
  const int tid = threadIdx.x;
  const int h = tid >> 6, lane = tid & 63;
  const int lr = lane & 15, lk = lane >> 4;
  const int hb = r & 3;

  if (tid < 169) bias_s[tid] = btable[tid * 4 + hb];

  const size_t gbase = (size_t)b * p.bstride;

  // K staging: 784 16B chunks (4 heads x 49 rows x 4 slots)
  for (int c = tid; c < 784; c += 256) {
    int hh = c / 196, rem = c - hh * 196;
    int row = rem >> 2, slot = rem & 3;
    int r7 = (row * 9363) >> 16, rm = row - r7 * 7;
    int n = (rh * 7 + r7) * p.ow + rw * 7 + rm;
    short8 v = *(const short8*)(p.kb + gbase + (size_t)n * p.rstride + hh * 32 + slot * 8);
    *(short8*)(Kls + hh * 2560 + row * 40 + slot * 8) = v;
  }
  // V staging, transposed + swizzled + zero-padded: 4096 bf16x2 jobs
  for (int j = tid; j < 4096; j += 256) {
    int pp = j & 63, dp = (j >> 6) & 15, hh = j >> 10;
    bf16 v0, v1;
    if (pp < 49) {
      int r7 = (pp * 9363) >> 16, rm = pp - r7 * 7;
      int n = (rh * 7 + r7) * p.ow + rw * 7 + rm;
      bf16x2 v2 = *(const bf16x2*)(p.vb + gbase + (size_t)n * p.rstride + hh * 32 + dp * 2);
      v0 = v2.x; v1 = v2.y;
    } else { v0 = __float2bfloat16(0.f); v1 = v0; }
    int d0 = dp * 2, d1 = d0 + 1;
    Vt[hh * 2048 + d0 * 64 + ((pp >> 3) ^ (d0 & 7)) * 8 + (pp & 7)] = v0;
    Vt[hh * 2048 + d1 * 64 + ((pp >> 3) ^ (d1 & 7)) * 8 + (pp & 7)] = v1;
  }

  // Q fragments straight from global (A-layout: row=lane&15, k=lk*8..+8)
  short8 qa[4];
#pragma unroll
  for (int it = 0; it < 4; ++it) {
    int pq = it * 16 + lr; pq = min(pq, 48);
    int r7 = (pq * 9363) >> 16, rm = pq - r7 * 7;
    int n = (rh * 7 + r7) * p.ow + rw * 7 + rm;
    qa[it] = *(const short8*)(p.qb + gbase + (size_t)n * p.rstride + h * 32 + lk * 8);
  }

  __syncthreads();

  // QK^T: 16 MFMAs (K=32, single k-step)
  f32x4 s[4][4];
  {
    short8 kf[4];
#pragma unroll
    for (int jt = 0; jt < 4; ++jt)
      kf[jt] = *(const short8*)(Kls + h * 2560 + (jt * 16 + lr) * 40 + lk * 8);
    const f32x4 z = {0.f, 0.f, 0.f, 0.f};
#pragma unroll
    for (int it = 0; it < 4; ++it)
#pragma unroll
      for (int jt = 0; jt < 4; ++jt)
        s[it][jt] = __builtin_amdgcn_mfma_f32_16x16x32_bf16(qa[it], kf[jt], z, 0, 0, 0);
  }

  // scale + bias + pad-mask + softmax (rows = lane&15 butterfly groups)
  const float scale = 0.17677669529663687f;
  const bool colpad = (lr != 0);               // jt==3: pp = 48+lr >= 49
  int pp7[4], ppm[4];
#pragma unroll
  for (int jt = 0; jt < 4; ++jt) {
    int pp = min(jt * 16 + lr, 48);
    pp7[jt] = (pp * 9363) >> 16; ppm[jt] = pp - pp7[jt] * 7;
  }
  float sm[4][4];
#pragma unroll
  for (int it = 0; it < 4; ++it)
#pragma unroll
    for (int t = 0; t < 4; ++t) {
      int pq = min(it * 16 + lk * 4 + t, 48);
      int q7 = (pq * 9363) >> 16, qm = pq - q7 * 7;
#pragma unroll
      for (int jt = 0; jt < 4; ++jt) {
        float bv = bias_s[(q7 - pp7[jt] + 6) * 13 + (qm - ppm[jt] + 6)];
        float v = fmaf(s[it][jt][t], scale, bv);
        if (jt == 3 && colpad) v = -1e30f;
        s[it][jt][t] = v;
      }
      float m = fmaxf(fmaxf(s[it][0][t], s[it][1][t]), fmaxf(s[it][2][t], s[it][3][t]));
      m = fmaxf(m, __shfl_xor(m, 1));
      m = fmaxf(m, __shfl_xor(m, 2));
      m = fmaxf(m, __shfl_xor(m, 4));
      m = fmaxf(m, __shfl_xor(m, 8));
      float ssum = 0.f;
#pragma unroll
      for (int jt = 0; jt < 4; ++jt) {
        float e = __expf(s[it][jt][t] - m);
        s[it][jt][t] = e; ssum += e;
      }
      ssum += __shfl_xor(ssum, 1);
      ssum += __shfl_xor(ssum, 2);
      ssum += __shfl_xor(ssum, 4);
      ssum += __shfl_xor(ssum, 8);
      sm[it][t] = 1.0f / ssum;
    }

  // P (unnormalized, <=1) -> LDS bf16, XOR-swizzled
#pragma unroll
  for (int it = 0; it < 4; ++it)
#pragma unroll
    for (int t = 0; t < 4; ++t) {
      int prow = it * 16 + lk * 4 + t;
#pragma unroll
      for (int jt = 0; jt < 4; ++jt) {
        int slot = (jt * 2 + (lr >> 3)) ^ (prow & 7);
        Pls[h * 4096 + prow * 64 + slot * 8 + (lr & 7)] = __float2bfloat16(s[it][jt][t]);
      }
    }
  __syncthreads();

  // PV: 16 MFMAs over 2 k-steps (pp 0..31, 32..63)
  f32x4 o[4][2] = {};
#pragma unroll
  for (int ks = 0; ks < 2; ++ks) {
    short8 pf[4], vf[2];
#pragma unroll
    for (int it = 0; it < 4; ++it) {
      int prow = it * 16 + lr;
      pf[it] = *(const short8*)(Pls + h * 4096 + prow * 64 + ((ks * 4 + lk) ^ (prow & 7)) * 8);
    }
#pragma unroll
    for (int jd = 0; jd < 2; ++jd) {
      int d = jd * 16 + lr;
      vf[jd] = *(const short8*)(Vt + h * 2048 + d * 64 + ((ks * 4 + lk) ^ (d & 7)) * 8);
    }
#pragma unroll
    for (int it = 0; it < 4; ++it)
#pragma unroll
      for (int jd = 0; jd < 2; ++jd)
        o[it][jd] = __builtin_amdgcn_mfma_f32_16x16x32_bf16(pf[it], vf[jd], o[it][jd], 0, 0, 0);
  }

  // scrambled output scatter (matches reference reshape semantics)
  const int c0 = (r & 3) * 32;
#pragma unroll
  for (int it = 0; it < 4; ++it)
#pragma unroll
    for (int t = 0; t < 4; ++t) {
      int prow = it * 16 + lk * 4 + t;
      if (prow < 49) {
        int m_out = (h * (p.R >> 2) + (r >> 2)) * 49 + prow;
        bf16* op = p.out + ((size_t)b * p.npos + m_out) * p.out_cstride + p.out_coffset + c0;
#pragma unroll
        for (int jd = 0; jd < 2; ++jd)
          op[jd * 16 + lr] = __float2bfloat16(o[it][jd][t] * sm[it][t]);
      }
    }
}

// ---------------- Fused bilinear upsample for both scales ----------------
__device__ __forceinline__ float2 bilerp2(const bf16* __restrict__ base, int dim, int h, int w, int cp)
{
  float r = (float)dim / 56.f;
  float uy = (h + 0.5f) * r - 0.5f;
  float ux = (w + 0.5f) * r - 0.5f;
  float fy0 = floorf(uy), fx0 = floorf(ux);
  int y0 = (int)fy0, x0 = (int)fx0;
  float fy = uy - fy0, fx = ux - fx0;
  int y0c = max(y0, 0), y1c = min(y0 + 1, dim - 1);
  int x0c = max(x0, 0), x1c = min(x0 + 1, dim - 1);
  bf16x2 v00 = *(const bf16x2*)(base + ((size_t)y0c * dim + x0c) * 128 + cp * 2);
  bf16x2 v01 = *(const bf16x2*)(base + ((size_t)y0c * dim + x1c) * 128 + cp * 2);
  bf16x2 v10 = *(const bf16x2*)(base + ((size_t)y1c * dim + x0c) * 128 + cp * 2);
  bf16x2 v11 = *(const bf16x2*)(base + ((size_t)y1c * dim + x1c) * 128 + cp * 2);
  float w00 = (1.f - fy) * (1.f - fx), w01 = (1.f - fy) * fx;
  float w10 = fy * (1.f - fx),        w11 = fy * fx;
  float2 o;
  o.x = w00 * __bfloat162float(v00.x) + w01 * __bfloat162float(v01.x) +
        w10 * __bfloat162float(v10.x) + w11 * __bfloat162float(v11.x);
  o.y = w00 * __bfloat162float(v00.y) + w01 * __bfloat162float(v01.y) +
        w10 * __bfloat162float(v10.y) + w11 * __bfloat162float(v11.y);
  return o;
}

__global__ __launch_bounds__(256) void upsample_both_kernel(const bf16* __restrict__ yb1,
                                                            const bf16* __restrict__ yb2,
                                                            bf16* __restrict__ fused)
{
  int t = blockIdx.x * 256 + threadIdx.x;
  int cp = t & 63;
  int pos = t >> 6;
  int n = pos % 3136, b = pos / 3136;
  int h = n / 56, w = n % 56;
  float2 s1 = bilerp2(yb1 + (size_t)b * 784 * 128, 28, h, w, cp);
  float2 s2 = bilerp2(yb2 + (size_t)b * 196 * 128, 14, h, w, cp);
  bf16* op = fused + (size_t)pos * 384;
  bf16x2 o1; o1.x = __float2bfloat16(s1.x); o1.y = __float2bfloat16(s1.y);
  bf16x2 o2; o2.x = __float2bfloat16(s2.x); o2.y = __float2bfloat16(s2.y);
  *(bf16x2*)(op + 128 + cp * 2) = o1;
  *(bf16x2*)(op + 256 + cp * 2) = o2;
}

extern "C" void kernel_launch(void* const* d_in, const int* in_sizes, int n_in,
                              void* d_out, int out_size, void* d_ws, size_t ws_size,
                              hipStream_t stream)
{
  const float* x      = (const float*)d_in[0];
  const float* w_qkv  = (const float*)d_in[1];
  const float* w_proj = (const float*)d_in[2];
  const float* b_proj = (const float*)d_in[3];
  const float* btable = (const float*)d_in[4];

  bf16* temp  = (bf16*)d_ws;                          // 50176 x 1152
  bf16* pool1 = temp  + (size_t)50176 * 1152;         // 3 x 16 x 784 x 128
  bf16* pool2 = pool1 + (size_t)3 * 16 * 784 * 128;   // 3 x 16 x 196 x 128
  bf16* fused = pool2 + (size_t)3 * 16 * 196 * 128;   // 50176 x 384 (also xb)
  bf16* ybuf1 = fused + (size_t)50176 * 384;          // 16 x 784 x 128
  bf16* ybuf2 = ybuf1 + (size_t)16 * 784 * 128;       // 16 x 196 x 128
  bf16* wqkvT = ybuf2 + (size_t)16 * 196 * 128;       // 1152 x 384
  bf16* wprojT= wqkvT + (size_t)1152 * 384;           // 384 x 384
  bf16* xb    = fused;   // x in bf16, dead before attention writes fused

  // 0) dtype prep
  cvt_f32_bf16_kernel<<<(50176 * 384 / 8 + 255) / 256, 256, 0, stream>>>(x, xb, 50176 * 384 / 8);
  transpose2_kernel<<<(1152 * 384 + 384 * 384) / 256, 256, 0, stream>>>(w_qkv, w_proj, wqkvT, wprojT);

  // 1) QKV projection: temp = xb @ wqkvT^T   (grid 9*392 = 3528, %8==0)
  gemm_mfma<bf16, false><<<3528, 256, 0, stream>>>(
      xb, wqkvT, nullptr, temp, 50176, 1152, 384, 9);

  // 2) pooling for scales 1,2 (mean + max), one launch
  pool_both_kernel<<<3 * 16 * 28 * 28 + 3 * 16 * 14 * 14, 128, 0, stream>>>(temp, pool1, pool2);

  // 3) MFMA window attention, all scales in one launch
  AttnP P0{temp, temp + 384, temp + 768, fused,
           64, 8, 56, 3136, 1152, 384, 0, 0, (long long)3136 * 1152};
  AttnP P1{pool1, pool1 + (size_t)16 * 784 * 128, pool1 + (size_t)2 * 16 * 784 * 128, ybuf1,
           16, 4, 28, 784, 128, 128, 0, 1024, (long long)784 * 128};
  AttnP P2{pool2, pool2 + (size_t)16 * 196 * 128, pool2 + (size_t)2 * 16 * 196 * 128, ybuf2,
           4, 2, 14, 196, 128, 128, 0, 1280, (long long)196 * 128};
  attn_mfma<<<1344, 256, 0, stream>>>(btable, P0, P1, P2);

  // 4) fused bilinear upsample into fused channels [128,256) and [256,384)
  upsample_both_kernel<<<16 * 3136 * 64 / 256, 256, 0, stream>>>(ybuf1, ybuf2, fused);

  // 5) output projection: out = fused @ wprojT^T + b_proj (fp32 out, grid 3*392=1176)
  gemm_mfma<float, true><<<1176, 256, 0, stream>>>(
      fused, wprojT, b_proj, (float*)d_out, 50176, 384, 384, 3);
}

// Round 8
// 206.675 us; speedup vs baseline: 4.5854x; 1.0170x over previous
//
#include <hip/hip_runtime.h>
#include <hip/hip_bf16.h>

typedef __hip_bfloat16 bf16;
typedef __hip_bfloat162 bf16x2;
typedef __attribute__((ext_vector_type(8))) short short8;
typedef __attribute__((ext_vector_type(4))) float f32x4;

__device__ __forceinline__ void storeOut(float* p, float v) { *p = v; }
__device__ __forceinline__ void storeOut(bf16* p, float v) { *p = __float2bfloat16(v); }

#define GLOAD_LDS16(g, l)                                              \
  __builtin_amdgcn_global_load_lds(                                    \
      (const __attribute__((address_space(1))) void*)(g),              \
      (__attribute__((address_space(3))) void*)(l), 16, 0, 0)

// ---------------- prep: fp32->bf16 convert of x + both weight transposes ----------------
__global__ __launch_bounds__(256) void prep_kernel(const float* __restrict__ x,
                                                   const float* __restrict__ w_qkv,
                                                   const float* __restrict__ w_proj,
                                                   bf16* __restrict__ xb,
                                                   bf16* __restrict__ wqkvT,
                                                   bf16* __restrict__ wprojT)
{
  int bid = blockIdx.x;
  if (bid < 9408) {                       // cvt: 50176*384 elems, 2048/block
    int i = bid * 256 + threadIdx.x;      // i < 2,408,448 (n8)
    const float4* p = (const float4*)x + (size_t)i * 2;
    float4 a = p[0], b = p[1];
    union { short8 v; bf16 h[8]; } u;
    u.h[0] = __float2bfloat16(a.x); u.h[1] = __float2bfloat16(a.y);
    u.h[2] = __float2bfloat16(a.z); u.h[3] = __float2bfloat16(a.w);
    u.h[4] = __float2bfloat16(b.x); u.h[5] = __float2bfloat16(b.y);
    u.h[6] = __float2bfloat16(b.z); u.h[7] = __float2bfloat16(b.w);
    *((short8*)xb + i) = u.v;
  } else {                                // transposes: 1152*384 + 384*384 elems
    int idx = (bid - 9408) * 256 + threadIdx.x;
    if (idx < 1152 * 384) {
      int n = idx / 384, k = idx - n * 384;
      wqkvT[idx] = __float2bfloat16(w_qkv[(size_t)k * 1152 + n]);
    } else {
      idx -= 1152 * 384;
      int n = idx / 384, k = idx - n * 384;
      wprojT[idx] = __float2bfloat16(w_proj[(size_t)k * 384 + n]);
    }
  }
}

// ---------------- MFMA GEMM: single-buffer BK=64 (round-4 verified config) ----------------
// 128x128 tile, 4 waves, 4x4x(2 k-slices) 16x16x32 bf16 MFMA per wave.
// Bank swizzle (both-sides, rule #21): LDS rows 128B (8 x 16B slots);
// slot q' holds global slot q'^(row&7); reads XOR the same.
template<typename TC, bool BIAS>
__global__ __launch_bounds__(256) void gemm_mfma(const bf16* __restrict__ A,
                                                 const bf16* __restrict__ Bt,
                                                 const float* __restrict__ bias,
                                                 TC* __restrict__ C,
                                                 int M, int N, int K, int nbx)
{
  __shared__ __align__(16) bf16 As[128 * 64];
  __shared__ __align__(16) bf16 Bs[128 * 64];
  const int tid = threadIdx.x;
  const int wave = tid >> 6, lane = tid & 63;
  const int cpx = gridDim.x >> 3;
  const int wg = (blockIdx.x & 7) * cpx + (blockIdx.x >> 3);
  const int by = wg / nbx, bx = wg - by * nbx;
  const int bm = by * 128, bn = bx * 128;
  const int wr = wave >> 1, wc = wave & 1;

  f32x4 acc[4][4] = {};

  const bf16* aP[4];
  const bf16* bP[4];
#pragma unroll
  for (int e = 0; e < 4; ++e) {
    int flat = e * 4096 + tid * 16;
    int r = flat >> 7;
    int q = ((flat >> 4) & 7) ^ (r & 7);
    aP[e] = A + (size_t)(bm + r) * K + q * 8;
    bP[e] = Bt + (size_t)(bn + r) * K + q * 8;
  }
  char* AsW = (char*)As + wave * 1024;
  char* BsW = (char*)Bs + wave * 1024;

  const int lr = lane & 15, lk = lane >> 4;
  const int rbA = (wr * 64 + lr) * 64;
  const int rbB = (wc * 64 + lr) * 64;
  const int q0 = ((lk    ) ^ (lr & 7)) * 8;
  const int q1 = ((4 + lk) ^ (lr & 7)) * 8;

  for (int k0 = 0; k0 < K; k0 += 64) {
#pragma unroll
    for (int e = 0; e < 4; ++e) GLOAD_LDS16(aP[e] + k0, AsW + e * 4096);
#pragma unroll
    for (int e = 0; e < 4; ++e) GLOAD_LDS16(bP[e] + k0, BsW + e * 4096);
    __syncthreads();
    short8 af0[4], af1[4], bf0[4], bf1[4];
#pragma unroll
    for (int i = 0; i < 4; ++i) {
      af0[i] = *(const short8*)(As + rbA + i * 1024 + q0);
      af1[i] = *(const short8*)(As + rbA + i * 1024 + q1);
    }
#pragma unroll
    for (int j = 0; j < 4; ++j) {
      bf0[j] = *(const short8*)(Bs + rbB + j * 1024 + q0);
      bf1[j] = *(const short8*)(Bs + rbB + j * 1024 + q1);
    }
#pragma unroll
    for (int i = 0; i < 4; ++i)
#pragma unroll
      for (int j = 0; j < 4; ++j) {
        acc[i][j] = __builtin_amdgcn_mfma_f32_16x16x32_bf16(af0[i], bf0[j], acc[i][j], 0, 0, 0);
        acc[i][j] = __builtin_amdgcn_mfma_f32_16x16x32_bf16(af1[i], bf1[j], acc[i][j], 0, 0, 0);
      }
    __syncthreads();
  }

  const int crow = bm + wr * 64 + lk * 4;
  const int ccol = bn + wc * 64 + lr;
#pragma unroll
  for (int j = 0; j < 4; ++j) {
    int col = ccol + j * 16;
    float bv = BIAS ? bias[col] : 0.f;
#pragma unroll
    for (int i = 0; i < 4; ++i)
#pragma unroll
      for (int t = 0; t < 4; ++t) {
        int row = crow + i * 16 + t;
        storeOut(&C[(size_t)row * N + col], acc[i][j][t] + bv);
      }
  }
}

// ---------------- Pooling (both scales): mean + max ----------------
__global__ __launch_bounds__(128) void pool_both_kernel(const bf16* __restrict__ temp,
                                                        bf16* __restrict__ pool1,
                                                        bf16* __restrict__ pool2)
{
  int blk = blockIdx.x;
  bf16* outp; int oh, k, isc;
  if (blk < 3 * 16 * 28 * 28) { outp = pool1; oh = 28; k = 2; isc = 1; }
  else { blk -= 3 * 16 * 28 * 28; outp = pool2; oh = 14; k = 4; isc = 2; }
  const int ow = oh;
  int c = threadIdx.x;
  int x = blk % ow; int t = blk / ow;
  int y = t % oh;  t /= oh;
  int b = t % 16;  int s = t / 16;
  float sum = 0.f, mx = -3.4e38f;
  float inv = 1.0f / (float)(k * k);
  for (int dy = 0; dy < k; ++dy)
    for (int dx = 0; dx < k; ++dx) {
      int h = y * k + dy, w = x * k + dx;
      float v = __bfloat162float(temp[((size_t)b * 3136 + h * 56 + w) * 1152 + s * 384 + isc * 128 + c]);
      sum += v; mx = fmaxf(mx, v);
    }
  outp[((size_t)(s * 16 + b) * oh * ow + y * ow + x) * 128 + c] = __float2bfloat16(sum * inv + mx);
}

// ---------------- MFMA window attention, all 3 scales in one launch ----------------
// Block = one window; 4 waves = 4 heads. P=49 padded to 64.
// LDS union: per-head 8KB block holds K (64x40, first 5KB) until QK^T, then P (64x64).
// Safe: regions disjoint per head; within a wave K ds_reads are consumed before P
// ds_writes issue (program order). LDS total ~50KB -> 3 blocks/CU.
struct AttnP {
  const bf16 *qb, *kb, *vb;
  bf16* out;
  int R, Rw, ow, npos, rstride, out_cstride, out_coffset, blk0;
  long long bstride;
};

__global__ __launch_bounds__(256) void attn_mfma(const float* __restrict__ btable,
                                                 AttnP P0, AttnP P1, AttnP P2)
{
  __shared__ __align__(16) bf16 KP[4 * 4096];      // [h]: K rows [64][40] then P [64][64]
  __shared__ __align__(16) bf16 Vt[4 * 2048];      // [h][d][pp] swizzled, pp>=49 zeroed
  __shared__ float bias_s[169];

  const AttnP p = (blockIdx.x >= (unsigned)P2.blk0) ? P2
                : (blockIdx.x >= (unsigned)P1.blk0) ? P1 : P0;
  const int blk = blockIdx.x - p.blk0;
  const int b = blk / p.R, r = blk % p.R;
  const int rh = r / p.Rw, rw = r % p.Rw;
  const int tid = threadIdx.x;
  const int h = tid >> 6, lane = tid & 63;
  const int lr = lane & 15, lk = lane >> 4;
  const int hb = r & 3;

  if (tid < 169) bias_s[tid] = btable[tid * 4 + hb];

  const size_t gbase = (size_t)b * p.bstride;

  // K staging: 784 16B chunks (4 heads x 49 rows x 4 slots)
  for (int c = tid; c < 784; c += 256) {
    int hh = c / 196, rem = c - hh * 196;
    int row = rem >> 2, slot = rem & 3;
    int r7 = (row * 9363) >> 16, rm = row - r7 * 7;
    int n = (rh * 7 + r7) * p.ow + rw * 7 + rm;
    short8 v = *(const short8*)(p.kb + gbase + (size_t)n * p.rstride + hh * 32 + slot * 8);
    *(short8*)(KP + hh * 4096 + row * 40 + slot * 8) = v;
  }
  // V staging, transposed + swizzled + zero-padded
  for (int j = tid; j < 4096; j += 256) {
    int pp = j & 63, dp = (j >> 6) & 15, hh = j >> 10;
    bf16 v0, v1;
    if (pp < 49) {
      int r7 = (pp * 9363) >> 16, rm = pp - r7 * 7;
      int n = (rh * 7 + r7) * p.ow + rw * 7 + rm;
      bf16x2 v2 = *(const bf16x2*)(p.vb + gbase + (size_t)n * p.rstride + hh * 32 + dp * 2);
      v0 = v2.x; v1 = v2.y;
    } else { v0 = __float2bfloat16(0.f); v1 = v0; }
    int d0 = dp * 2, d1 = d0 + 1;
    Vt[hh * 2048 + d0 * 64 + ((pp >> 3) ^ (d0 & 7)) * 8 + (pp & 7)] = v0;
    Vt[hh * 2048 + d1 * 64 + ((pp >> 3) ^ (d1 & 7)) * 8 + (pp & 7)] = v1;
  }

  // Q fragments straight from global (A-layout: row=lane&15, k=lk*8..+8)
  short8 qa[4];
#pragma unroll
  for (int it = 0; it < 4; ++it) {
    int pq = it * 16 + lr; pq = min(pq, 48);
    int r7 = (pq * 9363) >> 16, rm = pq - r7 * 7;
    int n = (rh * 7 + r7) * p.ow + rw * 7 + rm;
    qa[it] = *(const short8*)(p.qb + gbase + (size_t)n * p.rstride + h * 32 + lk * 8);
  }

  __syncthreads();

  // QK^T: 16 MFMAs (K=32, single k-step)
  f32x4 s[4][4];
  {
    short8 kf[4];
#pragma unroll
    for (int jt = 0; jt < 4; ++jt)
      kf[jt] = *(const short8*)(KP + h * 4096 + (jt * 16 + lr) * 40 + lk * 8);
    const f32x4 z = {0.f, 0.f, 0.f, 0.f};
    __builtin_amdgcn_s_setprio(1);
#pragma unroll
    for (int it = 0; it < 4; ++it)
#pragma unroll
      for (int jt = 0; jt < 4; ++jt)
        s[it][jt] = __builtin_amdgcn_mfma_f32_16x16x32_bf16(qa[it], kf[jt], z, 0, 0, 0);
    __builtin_amdgcn_s_setprio(0);
  }

  // scale + bias + pad-mask + softmax (rows = lane&15 butterfly groups)
  const float scale = 0.17677669529663687f;
  const bool colpad = (lr != 0);               // jt==3: pp = 48+lr >= 49
  int pp7[4], ppm[4];
#pragma unroll
  for (int jt = 0; jt < 4; ++jt) {
    int pp = min(jt * 16 + lr, 48);
    pp7[jt] = (pp * 9363) >> 16; ppm[jt] = pp - pp7[jt] * 7;
  }
  float sm[4][4];
#pragma unroll
  for (int it = 0; it < 4; ++it)
#pragma unroll
    for (int t = 0; t < 4; ++t) {
      int pq = min(it * 16 + lk * 4 + t, 48);
      int q7 = (pq * 9363) >> 16, qm = pq - q7 * 7;
#pragma unroll
      for (int jt = 0; jt < 4; ++jt) {
        float bv = bias_s[(q7 - pp7[jt] + 6) * 13 + (qm - ppm[jt] + 6)];
        float v = fmaf(s[it][jt][t], scale, bv);
        if (jt == 3 && colpad) v = -1e30f;
        s[it][jt][t] = v;
      }
      float m = fmaxf(fmaxf(s[it][0][t], s[it][1][t]), fmaxf(s[it][2][t], s[it][3][t]));
      m = fmaxf(m, __shfl_xor(m, 1));
      m = fmaxf(m, __shfl_xor(m, 2));
      m = fmaxf(m, __shfl_xor(m, 4));
      m = fmaxf(m, __shfl_xor(m, 8));
      float ssum = 0.f;
#pragma unroll
      for (int jt = 0; jt < 4; ++jt) {
        float e = __expf(s[it][jt][t] - m);
        s[it][jt][t] = e; ssum += e;
      }
      ssum += __shfl_xor(ssum, 1);
      ssum += __shfl_xor(ssum, 2);
      ssum += __shfl_xor(ssum, 4);
      ssum += __shfl_xor(ssum, 8);
      sm[it][t] = 1.0f / ssum;
    }

  // P (unnormalized, <=1) -> same per-head LDS block (K is dead), XOR-swizzled
#pragma unroll
  for (int it = 0; it < 4; ++it)
#pragma unroll
    for (int t = 0; t < 4; ++t) {
      int prow = it * 16 + lk * 4 + t;
#pragma unroll
      for (int jt = 0; jt < 4; ++jt) {
        int slot = (jt * 2 + (lr >> 3)) ^ (prow & 7);
        KP[h * 4096 + prow * 64 + slot * 8 + (lr & 7)] = __float2bfloat16(s[it][jt][t]);
      }
    }
  __syncthreads();

  // PV: 16 MFMAs over 2 k-steps (pp 0..31, 32..63)
  f32x4 o[4][2] = {};
#pragma unroll
  for (int ks = 0; ks < 2; ++ks) {
    short8 pf[4], vf[2];
#pragma unroll
    for (int it = 0; it < 4; ++it) {
      int prow = it * 16 + lr;
      pf[it] = *(const short8*)(KP + h * 4096 + prow * 64 + ((ks * 4 + lk) ^ (prow & 7)) * 8);
    }
#pragma unroll
    for (int jd = 0; jd < 2; ++jd) {
      int d = jd * 16 + lr;
      vf[jd] = *(const short8*)(Vt + h * 2048 + d * 64 + ((ks * 4 + lk) ^ (d & 7)) * 8);
    }
    __builtin_amdgcn_s_setprio(1);
#pragma unroll
    for (int it = 0; it < 4; ++it)
#pragma unroll
      for (int jd = 0; jd < 2; ++jd)
        o[it][jd] = __builtin_amdgcn_mfma_f32_16x16x32_bf16(pf[it], vf[jd], o[it][jd], 0, 0, 0);
    __builtin_amdgcn_s_setprio(0);
  }

  // scrambled output scatter (matches reference reshape semantics)
  const int c0 = (r & 3) * 32;
#pragma unroll
  for (int it = 0; it < 4; ++it)
#pragma unroll
    for (int t = 0; t < 4; ++t) {
      int prow = it * 16 + lk * 4 + t;
      if (prow < 49) {
        int m_out = (h * (p.R >> 2) + (r >> 2)) * 49 + prow;
        bf16* op = p.out + ((size_t)b * p.npos + m_out) * p.out_cstride + p.out_coffset + c0;
#pragma unroll
        for (int jd = 0; jd < 2; ++jd)
          op[jd * 16 + lr] = __float2bfloat16(o[it][jd][t] * sm[it][t]);
      }
    }
}

// ---------------- Fused bilinear upsample for both scales ----------------
__device__ __forceinline__ float2 bilerp2(const bf16* __restrict__ base, int dim, int h, int w, int cp)
{
  float r = (float)dim / 56.f;
  float uy = (h + 0.5f) * r - 0.5f;
  float ux = (w + 0.5f) * r - 0.5f;
  float fy0 = floorf(uy), fx0 = floorf(ux);
  int y0 = (int)fy0, x0 = (int)fx0;
  float fy = uy - fy0, fx = ux - fx0;
  int y0c = max(y0, 0), y1c = min(y0 + 1, dim - 1);
  int x0c = max(x0, 0), x1c = min(x0 + 1, dim - 1);
  bf16x2 v00 = *(const bf16x2*)(base + ((size_t)y0c * dim + x0c) * 128 + cp * 2);
  bf16x2 v01 = *(const bf16x2*)(base + ((size_t)y0c * dim + x1c) * 128 + cp * 2);
  bf16x2 v10 = *(const bf16x2*)(base + ((size_t)y1c * dim + x0c) * 128 + cp * 2);
  bf16x2 v11 = *(const bf16x2*)(base + ((size_t)y1c * dim + x1c) * 128 + cp * 2);
  float w00 = (1.f - fy) * (1.f - fx), w01 = (1.f - fy) * fx;
  float w10 = fy * (1.f - fx),        w11 = fy * fx;
  float2 o;
  o.x = w00 * __bfloat162float(v00.x) + w01 * __bfloat162float(v01.x) +
        w10 * __bfloat162float(v10.x) + w11 * __bfloat162float(v11.x);
  o.y = w00 * __bfloat162float(v00.y) + w01 * __bfloat162float(v01.y) +
        w10 * __bfloat162float(v10.y) + w11 * __bfloat162float(v11.y);
  return o;
}

__global__ __launch_bounds__(256) void upsample_both_kernel(const bf16* __restrict__ yb1,
                                                            const bf16* __restrict__ yb2,
                                                            bf16* __restrict__ fused)
{
  int t = blockIdx.x * 256 + threadIdx.x;
  int cp = t & 63;
  int pos = t >> 6;
  int n = pos % 3136, b = pos / 3136;
  int h = n / 56, w = n % 56;
  float2 s1 = bilerp2(yb1 + (size_t)b * 784 * 128, 28, h, w, cp);
  float2 s2 = bilerp2(yb2 + (size_t)b * 196 * 128, 14, h, w, cp);
  bf16* op = fused + (size_t)pos * 384;
  bf16x2 o1; o1.x = __float2bfloat16(s1.x); o1.y = __float2bfloat16(s1.y);
  bf16x2 o2; o2.x = __float2bfloat16(s2.x); o2.y = __float2bfloat16(s2.y);
  *(bf16x2*)(op + 128 + cp * 2) = o1;
  *(bf16x2*)(op + 256 + cp * 2) = o2;
}

extern "C" void kernel_launch(void* const* d_in, const int* in_sizes, int n_in,
                              void* d_out, int out_size, void* d_ws, size_t ws_size,
                              hipStream_t stream)
{
  const float* x      = (const float*)d_in[0];
  const float* w_qkv  = (const float*)d_in[1];
  const float* w_proj = (const float*)d_in[2];
  const float* b_proj = (const float*)d_in[3];
  const float* btable = (const float*)d_in[4];

  bf16* temp  = (bf16*)d_ws;                          // 50176 x 1152
  bf16* pool1 = temp  + (size_t)50176 * 1152;         // 3 x 16 x 784 x 128
  bf16* pool2 = pool1 + (size_t)3 * 16 * 784 * 128;   // 3 x 16 x 196 x 128
  bf16* fused = pool2 + (size_t)3 * 16 * 196 * 128;   // 50176 x 384 (also xb)
  bf16* ybuf1 = fused + (size_t)50176 * 384;          // 16 x 784 x 128
  bf16* ybuf2 = ybuf1 + (size_t)16 * 784 * 128;       // 16 x 196 x 128
  bf16* wqkvT = ybuf2 + (size_t)16 * 196 * 128;       // 1152 x 384
  bf16* wprojT= wqkvT + (size_t)1152 * 384;           // 384 x 384
  bf16* xb    = fused;   // x in bf16, dead before attention writes fused

  // 0) prep: cvt + transposes in one launch
  prep_kernel<<<9408 + 2304, 256, 0, stream>>>(x, w_qkv, w_proj, xb, wqkvT, wprojT);

  // 1) QKV projection: temp = xb @ wqkvT^T   (grid 9*392 = 3528, %8==0)
  gemm_mfma<bf16, false><<<3528, 256, 0, stream>>>(
      xb, wqkvT, nullptr, temp, 50176, 1152, 384, 9);

  // 2) pooling for scales 1,2 (mean + max), one launch
  pool_both_kernel<<<3 * 16 * 28 * 28 + 3 * 16 * 14 * 14, 128, 0, stream>>>(temp, pool1, pool2);

  // 3) MFMA window attention, all scales in one launch
  AttnP P0{temp, temp + 384, temp + 768, fused,
           64, 8, 56, 3136, 1152, 384, 0, 0, (long long)3136 * 1152};
  AttnP P1{pool1, pool1 + (size_t)16 * 784 * 128, pool1 + (size_t)2 * 16 * 784 * 128, ybuf1,
           16, 4, 28, 784, 128, 128, 0, 1024, (long long)784 * 128};
  AttnP P2{pool2, pool2 + (size_t)16 * 196 * 128, pool2 + (size_t)2 * 16 * 196 * 128, ybuf2,
           4, 2, 14, 196, 128, 128, 0, 1280, (long long)196 * 128};
  attn_mfma<<<1344, 256, 0, stream>>>(btable, P0, P1, P2);

  // 4) fused bilinear upsample into fused channels [128,256) and [256,384)
  upsample_both_kernel<<<16 * 3136 * 64 / 256, 256, 0, stream>>>(ybuf1, ybuf2, fused);

  // 5) output projection: out = fused @ wprojT^T + b_proj (fp32 out, grid 3*392=1176)
  gemm_mfma<float, true><<<1176, 256, 0, stream>>>(
      fused, wprojT, b_proj, (float*)d_out, 50176, 384, 384, 3);
}

// Round 9
// 204.976 us; speedup vs baseline: 4.6234x; 1.0083x over previous
//
#include <hip/hip_runtime.h>
#include <hip/hip_bf16.h>

typedef __hip_bfloat16 bf16;
typedef __hip_bfloat162 bf16x2;
typedef __attribute__((ext_vector_type(8))) short short8;
typedef __attribute__((ext_vector_type(4))) float f32x4;

__device__ __forceinline__ void storeOut(float* p, float v) { *p = v; }
__device__ __forceinline__ void storeOut(bf16* p, float v) { *p = __float2bfloat16(v); }

#define GLOAD_LDS16(g, l)                                              \
  __builtin_amdgcn_global_load_lds(                                    \
      (const __attribute__((address_space(1))) void*)(g),              \
      (__attribute__((address_space(3))) void*)(l), 16, 0, 0)

// ---------------- prep: fp32->bf16 convert of x + both weight transposes ----------------
__global__ __launch_bounds__(256) void prep_kernel(const float* __restrict__ x,
                                                   const float* __restrict__ w_qkv,
                                                   const float* __restrict__ w_proj,
                                                   bf16* __restrict__ xb,
                                                   bf16* __restrict__ wqkvT,
                                                   bf16* __restrict__ wprojT)
{
  int bid = blockIdx.x;
  if (bid < 9408) {                       // cvt: 50176*384 elems, 2048/block
    int i = bid * 256 + threadIdx.x;
    const float4* p = (const float4*)x + (size_t)i * 2;
    float4 a = p[0], b = p[1];
    union { short8 v; bf16 h[8]; } u;
    u.h[0] = __float2bfloat16(a.x); u.h[1] = __float2bfloat16(a.y);
    u.h[2] = __float2bfloat16(a.z); u.h[3] = __float2bfloat16(a.w);
    u.h[4] = __float2bfloat16(b.x); u.h[5] = __float2bfloat16(b.y);
    u.h[6] = __float2bfloat16(b.z); u.h[7] = __float2bfloat16(b.w);
    *((short8*)xb + i) = u.v;
  } else {                                // transposes: 1152*384 + 384*384 elems
    int idx = (bid - 9408) * 256 + threadIdx.x;
    if (idx < 1152 * 384) {
      int n = idx / 384, k = idx - n * 384;
      wqkvT[idx] = __float2bfloat16(w_qkv[(size_t)k * 1152 + n]);
    } else {
      idx -= 1152 * 384;
      int n = idx / 384, k = idx - n * 384;
      wprojT[idx] = __float2bfloat16(w_proj[(size_t)k * 384 + n]);
    }
  }
}

// ---------------- MFMA GEMM: 256x128 tile, 8 waves, BK=64, single-buffer ----------------
// Wave tile 64x64 (4x4x2 16x16x32 MFMA) — identical fragment code to the verified
// 128x128 kernel; only the wave grid (4Mx2N) and staging counts change.
// LDS 48KB -> 3 blocks/CU (24 waves). LDS bytes/FLOP halved vs 128x128.
// Bank swizzle (both-sides, rule #21): rows 128B (8 x 16B slots), slot q'^(row&7).
// XCD swizzle: m204 bijective variant (grid not necessarily %8).
template<typename TC, bool BIAS>
__global__ __launch_bounds__(512) void gemm_mfma(const bf16* __restrict__ A,
                                                 const bf16* __restrict__ Bt,
                                                 const float* __restrict__ bias,
                                                 TC* __restrict__ C,
                                                 int M, int N, int K, int nbx)
{
  __shared__ __align__(16) bf16 As[256 * 64];   // 32 KB
  __shared__ __align__(16) bf16 Bs[128 * 64];   // 16 KB
  const int tid = threadIdx.x;
  const int wave = tid >> 6, lane = tid & 63;
  // bijective XCD swizzle (m204)
  const int nwg = gridDim.x;
  const int qc = nwg >> 3, rr = nwg & 7;
  const int xcd = blockIdx.x & 7, jj = blockIdx.x >> 3;
  const int wg = (xcd < rr ? xcd * (qc + 1) : rr * (qc + 1) + (xcd - rr) * qc) + jj;
  const int by = wg / nbx, bx = wg - by * nbx;
  const int bm = by * 256, bn = bx * 128;
  const int wr = wave >> 1, wc = wave & 1;      // 4 x 2 wave grid

  f32x4 acc[4][4] = {};

  // staging: A = 4 chunks of 8KB, B = 2 chunks. flat byte F = e*8192 + tid*16
  // -> LDS row F>>7, slot (F>>4)&7; global source slot XOR-swizzled.
  const bf16* aP[4];
  const bf16* bP[2];
#pragma unroll
  for (int e = 0; e < 4; ++e) {
    int flat = e * 8192 + tid * 16;
    int r = flat >> 7;
    int q = ((flat >> 4) & 7) ^ (r & 7);
    aP[e] = A + (size_t)(bm + r) * K + q * 8;
  }
#pragma unroll
  for (int e = 0; e < 2; ++e) {
    int flat = e * 8192 + tid * 16;
    int r = flat >> 7;
    int q = ((flat >> 4) & 7) ^ (r & 7);
    bP[e] = Bt + (size_t)(bn + r) * K + q * 8;
  }
  char* AsW = (char*)As + wave * 1024;   // wave-uniform dest, linear
  char* BsW = (char*)Bs + wave * 1024;

  const int lr = lane & 15, lk = lane >> 4;
  const int rbA = (wr * 64 + lr) * 64;
  const int rbB = (wc * 64 + lr) * 64;
  const int q0 = ((lk    ) ^ (lr & 7)) * 8;
  const int q1 = ((4 + lk) ^ (lr & 7)) * 8;

  for (int k0 = 0; k0 < K; k0 += 64) {
#pragma unroll
    for (int e = 0; e < 4; ++e) GLOAD_LDS16(aP[e] + k0, AsW + e * 8192);
#pragma unroll
    for (int e = 0; e < 2; ++e) GLOAD_LDS16(bP[e] + k0, BsW + e * 8192);
    __syncthreads();
    short8 af0[4], af1[4], bf0[4], bf1[4];
#pragma unroll
    for (int i = 0; i < 4; ++i) {
      af0[i] = *(const short8*)(As + rbA + i * 1024 + q0);
      af1[i] = *(const short8*)(As + rbA + i * 1024 + q1);
    }
#pragma unroll
    for (int j = 0; j < 4; ++j) {
      bf0[j] = *(const short8*)(Bs + rbB + j * 1024 + q0);
      bf1[j] = *(const short8*)(Bs + rbB + j * 1024 + q1);
    }
#pragma unroll
    for (int i = 0; i < 4; ++i)
#pragma unroll
      for (int j = 0; j < 4; ++j) {
        acc[i][j] = __builtin_amdgcn_mfma_f32_16x16x32_bf16(af0[i], bf0[j], acc[i][j], 0, 0, 0);
        acc[i][j] = __builtin_amdgcn_mfma_f32_16x16x32_bf16(af1[i], bf1[j], acc[i][j], 0, 0, 0);
      }
    __syncthreads();
  }

  const int crow = bm + wr * 64 + lk * 4;
  const int ccol = bn + wc * 64 + lr;
#pragma unroll
  for (int j = 0; j < 4; ++j) {
    int col = ccol + j * 16;
    float bv = BIAS ? bias[col] : 0.f;
#pragma unroll
    for (int i = 0; i < 4; ++i)
#pragma unroll
      for (int t = 0; t < 4; ++t) {
        int row = crow + i * 16 + t;
        storeOut(&C[(size_t)row * N + col], acc[i][j][t] + bv);
      }
  }
}

// ---------------- Pooling (both scales): mean + max ----------------
__global__ __launch_bounds__(128) void pool_both_kernel(const bf16* __restrict__ temp,
                                                        bf16* __restrict__ pool1,
                                                        bf16* __restrict__ pool2)
{
  int blk = blockIdx.x;
  bf16* outp; int oh, k, isc;
  if (blk < 3 * 16 * 28 * 28) { outp = pool1; oh = 28; k = 2; isc = 1; }
  else { blk -= 3 * 16 * 28 * 28; outp = pool2; oh = 14; k = 4; isc = 2; }
  const int ow = oh;
  int c = threadIdx.x;
  int x = blk % ow; int t = blk / ow;
  int y = t % oh;  t /= oh;
  int b = t % 16;  int s = t / 16;
  float sum = 0.f, mx = -3.4e38f;
  float inv = 1.0f / (float)(k * k);
  for (int dy = 0; dy < k; ++dy)
    for (int dx = 0; dx < k; ++dx) {
      int h = y * k + dy, w = x * k + dx;
      float v = __bfloat162float(temp[((size_t)b * 3136 + h * 56 + w) * 1152 + s * 384 + isc * 128 + c]);
      sum += v; mx = fmaxf(mx, v);
    }
  outp[((size_t)(s * 16 + b) * oh * ow + y * ow + x) * 128 + c] = __float2bfloat16(sum * inv + mx);
}

// ---------------- MFMA window attention, all 3 scales in one launch ----------------
struct AttnP {
  const bf16 *qb, *kb, *vb;
  bf16* out;
  int R, Rw, ow, npos, rstride, out_cstride, out_coffset, blk0;
  long long bstride;
};

__global__ __launch_bounds__(256) void attn_mfma(const float* __restrict__ btable,
                                                 AttnP P0, AttnP P1, AttnP P2)
{
  __shared__ __align__(16) bf16 KP[4 * 4096];      // [h]: K rows [64][40] then P [64][64]
  __shared__ __align__(16) bf16 Vt[4 * 2048];      // [h][d][pp] swizzled, pp>=49 zeroed
  __shared__ float bias_s[169];

  const AttnP p = (blockIdx.x >= (unsigned)P2.blk0) ? P2
                : (blockIdx.x >= (unsigned)P1.blk0) ? P1 : P0;
  const int blk = blockIdx.x - p.blk0;
  const int b = blk / p.R, r = blk % p.R;
  const int rh = r / p.Rw, rw = r % p.Rw;
  const int tid = threadIdx.x;
  const int h = tid >> 6, lane = tid & 63;
  const int lr = lane & 15, lk = lane >> 4;
  const int hb = r & 3;

  if (tid < 169) bias_s[tid] = btable[tid * 4 + hb];

  const size_t gbase = (size_t)b * p.bstride;

  // K staging: 784 16B chunks (4 heads x 49 rows x 4 slots)
  for (int c = tid; c < 784; c += 256) {
    int hh = c / 196, rem = c - hh * 196;
    int row = rem >> 2, slot = rem & 3;
    int r7 = (row * 9363) >> 16, rm = row - r7 * 7;
    int n = (rh * 7 + r7) * p.ow + rw * 7 + rm;
    short8 v = *(const short8*)(p.kb + gbase + (size_t)n * p.rstride + hh * 32 + slot * 8);
    *(short8*)(KP + hh * 4096 + row * 40 + slot * 8) = v;
  }
  // V staging, transposed + swizzled + zero-padded
  for (int j = tid; j < 4096; j += 256) {
    int pp = j & 63, dp = (j >> 6) & 15, hh = j >> 10;
    bf16 v0, v1;
    if (pp < 49) {
      int r7 = (pp * 9363) >> 16, rm = pp - r7 * 7;
      int n = (rh * 7 + r7) * p.ow + rw * 7 + rm;
      bf16x2 v2 = *(const bf16x2*)(p.vb + gbase + (size_t)n * p.rstride + hh * 32 + dp * 2);
      v0 = v2.x; v1 = v2.y;
    } else { v0 = __float2bfloat16(0.f); v1 = v0; }
    int d0 = dp * 2, d1 = d0 + 1;
    Vt[hh * 2048 + d0 * 64 + ((pp >> 3) ^ (d0 & 7)) * 8 + (pp & 7)] = v0;
    Vt[hh * 2048 + d1 * 64 + ((pp >> 3) ^ (d1 & 7)) * 8 + (pp & 7)] = v1;
  }

  // Q fragments straight from global (A-layout: row=lane&15, k=lk*8..+8)
  short8 qa[4];
#pragma unroll
  for (int it = 0; it < 4; ++it) {
    int pq = it * 16 + lr; pq = min(pq, 48);
    int r7 = (pq * 9363) >> 16, rm = pq - r7 * 7;
    int n = (rh * 7 + r7) * p.ow + rw * 7 + rm;
    qa[it] = *(const short8*)(p.qb + gbase + (size_t)n * p.rstride + h * 32 + lk * 8);
  }

  __syncthreads();

  // QK^T: 16 MFMAs (K=32, single k-step)
  f32x4 s[4][4];
  {
    short8 kf[4];
#pragma unroll
    for (int jt = 0; jt < 4; ++jt)
      kf[jt] = *(const short8*)(KP + h * 4096 + (jt * 16 + lr) * 40 + lk * 8);
    const f32x4 z = {0.f, 0.f, 0.f, 0.f};
    __builtin_amdgcn_s_setprio(1);
#pragma unroll
    for (int it = 0; it < 4; ++it)
#pragma unroll
      for (int jt = 0; jt < 4; ++jt)
        s[it][jt] = __builtin_amdgcn_mfma_f32_16x16x32_bf16(qa[it], kf[jt], z, 0, 0, 0);
    __builtin_amdgcn_s_setprio(0);
  }

  // scale + bias + pad-mask + softmax (rows = lane&15 butterfly groups)
  const float scale = 0.17677669529663687f;
  const bool colpad = (lr != 0);               // jt==3: pp = 48+lr >= 49
  int pp7[4], ppm[4];
#pragma unroll
  for (int jt = 0; jt < 4; ++jt) {
    int pp = min(jt * 16 + lr, 48);
    pp7[jt] = (pp * 9363) >> 16; ppm[jt] = pp - pp7[jt] * 7;
  }
  float sm[4][4];
#pragma unroll
  for (int it = 0; it < 4; ++it)
#pragma unroll
    for (int t = 0; t < 4; ++t) {
      int pq = min(it * 16 + lk * 4 + t, 48);
      int q7 = (pq * 9363) >> 16, qm = pq - q7 * 7;
#pragma unroll
      for (int jt = 0; jt < 4; ++jt) {
        float bv = bias_s[(q7 - pp7[jt] + 6) * 13 + (qm - ppm[jt] + 6)];
        float v = fmaf(s[it][jt][t], scale, bv);
        if (jt == 3 && colpad) v = -1e30f;
        s[it][jt][t] = v;
      }
      float m = fmaxf(fmaxf(s[it][0][t], s[it][1][t]), fmaxf(s[it][2][t], s[it][3][t]));
      m = fmaxf(m, __shfl_xor(m, 1));
      m = fmaxf(m, __shfl_xor(m, 2));
      m = fmaxf(m, __shfl_xor(m, 4));
      m = fmaxf(m, __shfl_xor(m, 8));
      float ssum = 0.f;
#pragma unroll
      for (int jt = 0; jt < 4; ++jt) {
        float e = __expf(s[it][jt][t] - m);
        s[it][jt][t] = e; ssum += e;
      }
      ssum += __shfl_xor(ssum, 1);
      ssum += __shfl_xor(ssum, 2);
      ssum += __shfl_xor(ssum, 4);
      ssum += __shfl_xor(ssum, 8);
      sm[it][t] = 1.0f / ssum;
    }

  // P (unnormalized, <=1) -> same per-head LDS block (K is dead), XOR-swizzled
#pragma unroll
  for (int it = 0; it < 4; ++it)
#pragma unroll
    for (int t = 0; t < 4; ++t) {
      int prow = it * 16 + lk * 4 + t;
#pragma unroll
      for (int jt = 0; jt < 4; ++jt) {
        int slot = (jt * 2 + (lr >> 3)) ^ (prow & 7);
        KP[h * 4096 + prow * 64 + slot * 8 + (lr & 7)] = __float2bfloat16(s[it][jt][t]);
      }
    }
  __syncthreads();

  // PV: 16 MFMAs over 2 k-steps (pp 0..31, 32..63)
  f32x4 o[4][2] = {};
#pragma unroll
  for (int ks = 0; ks < 2; ++ks) {
    short8 pf[4], vf[2];
#pragma unroll
    for (int it = 0; it < 4; ++it) {
      int prow = it * 16 + lr;
      pf[it] = *(const short8*)(KP + h * 4096 + prow * 64 + ((ks * 4 + lk) ^ (prow & 7)) * 8);
    }
#pragma unroll
    for (int jd = 0; jd < 2; ++jd) {
      int d = jd * 16 + lr;
      vf[jd] = *(const short8*)(Vt + h * 2048 + d * 64 + ((ks * 4 + lk) ^ (d & 7)) * 8);
    }
    __builtin_amdgcn_s_setprio(1);
#pragma unroll
    for (int it = 0; it < 4; ++it)
#pragma unroll
      for (int jd = 0; jd < 2; ++jd)
        o[it][jd] = __builtin_amdgcn_mfma_f32_16x16x32_bf16(pf[it], vf[jd], o[it][jd], 0, 0, 0);
    __builtin_amdgcn_s_setprio(0);
  }

  // scrambled output scatter (matches reference reshape semantics)
  const int c0 = (r & 3) * 32;
#pragma unroll
  for (int it = 0; it < 4; ++it)
#pragma unroll
    for (int t = 0; t < 4; ++t) {
      int prow = it * 16 + lk * 4 + t;
      if (prow < 49) {
        int m_out = (h * (p.R >> 2) + (r >> 2)) * 49 + prow;
        bf16* op = p.out + ((size_t)b * p.npos + m_out) * p.out_cstride + p.out_coffset + c0;
#pragma unroll
        for (int jd = 0; jd < 2; ++jd)
          op[jd * 16 + lr] = __float2bfloat16(o[it][jd][t] * sm[it][t]);
      }
    }
}

// ---------------- Fused bilinear upsample for both scales ----------------
__device__ __forceinline__ float2 bilerp2(const bf16* __restrict__ base, int dim, int h, int w, int cp)
{
  float r = (float)dim / 56.f;
  float uy = (h + 0.5f) * r - 0.5f;
  float ux = (w + 0.5f) * r - 0.5f;
  float fy0 = floorf(uy), fx0 = floorf(ux);
  int y0 = (int)fy0, x0 = (int)fx0;
  float fy = uy - fy0, fx = ux - fx0;
  int y0c = max(y0, 0), y1c = min(y0 + 1, dim - 1);
  int x0c = max(x0, 0), x1c = min(x0 + 1, dim - 1);
  bf16x2 v00 = *(const bf16x2*)(base + ((size_t)y0c * dim + x0c) * 128 + cp * 2);
  bf16x2 v01 = *(const bf16x2*)(base + ((size_t)y0c * dim + x1c) * 128 + cp * 2);
  bf16x2 v10 = *(const bf16x2*)(base + ((size_t)y1c * dim + x0c) * 128 + cp * 2);
  bf16x2 v11 = *(const bf16x2*)(base + ((size_t)y1c * dim + x1c) * 128 + cp * 2);
  float w00 = (1.f - fy) * (1.f - fx), w01 = (1.f - fy) * fx;
  float w10 = fy * (1.f - fx),        w11 = fy * fx;
  float2 o;
  o.x = w00 * __bfloat162float(v00.x) + w01 * __bfloat162float(v01.x) +
        w10 * __bfloat162float(v10.x) + w11 * __bfloat162float(v11.x);
  o.y = w00 * __bfloat162float(v00.y) + w01 * __bfloat162float(v01.y) +
        w10 * __bfloat162float(v10.y) + w11 * __bfloat162float(v11.y);
  return o;
}

__global__ __launch_bounds__(256) void upsample_both_kernel(const bf16* __restrict__ yb1,
                                                            const bf16* __restrict__ yb2,
                                                            bf16* __restrict__ fused)
{
  int t = blockIdx.x * 256 + threadIdx.x;
  int cp = t & 63;
  int pos = t >> 6;
  int n = pos % 3136, b = pos / 3136;
  int h = n / 56, w = n % 56;
  float2 s1 = bilerp2(yb1 + (size_t)b * 784 * 128, 28, h, w, cp);
  float2 s2 = bilerp2(yb2 + (size_t)b * 196 * 128, 14, h, w, cp);
  bf16* op = fused + (size_t)pos * 384;
  bf16x2 o1; o1.x = __float2bfloat16(s1.x); o1.y = __float2bfloat16(s1.y);
  bf16x2 o2; o2.x = __float2bfloat16(s2.x); o2.y = __float2bfloat16(s2.y);
  *(bf16x2*)(op + 128 + cp * 2) = o1;
  *(bf16x2*)(op + 256 + cp * 2) = o2;
}

extern "C" void kernel_launch(void* const* d_in, const int* in_sizes, int n_in,
                              void* d_out, int out_size, void* d_ws, size_t ws_size,
                              hipStream_t stream)
{
  const float* x      = (const float*)d_in[0];
  const float* w_qkv  = (const float*)d_in[1];
  const float* w_proj = (const float*)d_in[2];
  const float* b_proj = (const float*)d_in[3];
  const float* btable = (const float*)d_in[4];

  bf16* temp  = (bf16*)d_ws;                          // 50176 x 1152
  bf16* pool1 = temp  + (size_t)50176 * 1152;         // 3 x 16 x 784 x 128
  bf16* pool2 = pool1 + (size_t)3 * 16 * 784 * 128;   // 3 x 16 x 196 x 128
  bf16* fused = pool2 + (size_t)3 * 16 * 196 * 128;   // 50176 x 384 (also xb)
  bf16* ybuf1 = fused + (size_t)50176 * 384;          // 16 x 784 x 128
  bf16* ybuf2 = ybuf1 + (size_t)16 * 784 * 128;       // 16 x 196 x 128
  bf16* wqkvT = ybuf2 + (size_t)16 * 196 * 128;       // 1152 x 384
  bf16* wprojT= wqkvT + (size_t)1152 * 384;           // 384 x 384
  bf16* xb    = fused;   // x in bf16, dead before attention writes fused

  // 0) prep: cvt + transposes in one launch
  prep_kernel<<<9408 + 2304, 256, 0, stream>>>(x, w_qkv, w_proj, xb, wqkvT, wprojT);

  // 1) QKV projection: temp = xb @ wqkvT^T  (196 x 9 = 1764 blocks, 512 thr)
  gemm_mfma<bf16, false><<<1764, 512, 0, stream>>>(
      xb, wqkvT, nullptr, temp, 50176, 1152, 384, 9);

  // 2) pooling for scales 1,2 (mean + max), one launch
  pool_both_kernel<<<3 * 16 * 28 * 28 + 3 * 16 * 14 * 14, 128, 0, stream>>>(temp, pool1, pool2);

  // 3) MFMA window attention, all scales in one launch
  AttnP P0{temp, temp + 384, temp + 768, fused,
           64, 8, 56, 3136, 1152, 384, 0, 0, (long long)3136 * 1152};
  AttnP P1{pool1, pool1 + (size_t)16 * 784 * 128, pool1 + (size_t)2 * 16 * 784 * 128, ybuf1,
           16, 4, 28, 784, 128, 128, 0, 1024, (long long)784 * 128};
  AttnP P2{pool2, pool2 + (size_t)16 * 196 * 128, pool2 + (size_t)2 * 16 * 196 * 128, ybuf2,
           4, 2, 14, 196, 128, 128, 0, 1280, (long long)196 * 128};
  attn_mfma<<<1344, 256, 0, stream>>>(btable, P0, P1, P2);

  // 4) fused bilinear upsample into fused channels [128,256) and [256,384)
  upsample_both_kernel<<<16 * 3136 * 64 / 256, 256, 0, stream>>>(ybuf1, ybuf2, fused);

  // 5) output projection: out = fused @ wprojT^T + b_proj (196 x 3 = 588 blocks)
  gemm_mfma<float, true><<<588, 512, 0, stream>>>(
      fused, wprojT, b_proj, (float*)d_out, 50176, 384, 384, 3);
}